// Round 8
// baseline (1519.600 us; speedup 1.0000x reference)
//
#include <hip/hip_runtime.h>

using half4  = __attribute__((ext_vector_type(4))) _Float16;
using half8  = __attribute__((ext_vector_type(8))) _Float16;
using floatx4 = __attribute__((ext_vector_type(4))) float;

__device__ __forceinline__ void gl_lds16(const _Float16* g, _Float16* l)
{
  __builtin_amdgcn_global_load_lds(
      (const __attribute__((address_space(1))) void*)g,
      (__attribute__((address_space(3))) void*)l, 16, 0, 0);
}

// ---------------- MFMA fp16 GEMM (128x128 tile): C = A @ Bt^T + bias
__global__ __launch_bounds__(256) void gemm_h(
    const _Float16* __restrict__ A, const _Float16* __restrict__ Bt,
    const float* __restrict__ bias, _Float16* __restrict__ C,
    int M, int N, int K, int ldC, int relu)
{
  __shared__ _Float16 As[128 * 32];
  __shared__ _Float16 Bs[128 * 32];
  int tid = threadIdx.x;
  int lane = tid & 63, wave = tid >> 6;
  long bm0 = (long)blockIdx.y * 128;
  int bn0 = blockIdx.x * 128;
  int wm = (wave & 1) * 64, wn = (wave >> 1) * 64;
  int srow = wave * 16 + (lane >> 2);
  int scol = (lane & 3) * 8;
  const _Float16* aA0 = A + (bm0 + srow) * (long)K + scol;
  const _Float16* aA1 = aA0 + 64 * (long)K;
  const _Float16* aB0 = Bt + (bn0 + srow) * (long)K + scol;
  const _Float16* aB1 = aB0 + 64 * (long)K;
  _Float16* lA0 = As + wave * 512;
  _Float16* lA1 = As + 2048 + wave * 512;
  _Float16* lB0 = Bs + wave * 512;
  _Float16* lB1 = Bs + 2048 + wave * 512;
  int mrow = lane & 15, quad = lane >> 4;
  floatx4 acc[4][4];
#pragma unroll
  for (int i = 0; i < 4; ++i)
#pragma unroll
    for (int j = 0; j < 4; ++j) acc[i][j] = (floatx4){0.f, 0.f, 0.f, 0.f};

  for (int kt = 0; kt < K; kt += 32) {
    __syncthreads();
    gl_lds16(aA0 + kt, lA0);
    gl_lds16(aA1 + kt, lA1);
    gl_lds16(aB0 + kt, lB0);
    gl_lds16(aB1 + kt, lB1);
    __syncthreads();
    half8 af[4], bf[4];
#pragma unroll
    for (int i = 0; i < 4; ++i)
      af[i] = *(const half8*)&As[(wm + 16 * i + mrow) * 32 + quad * 8];
#pragma unroll
    for (int j = 0; j < 4; ++j)
      bf[j] = *(const half8*)&Bs[(wn + 16 * j + mrow) * 32 + quad * 8];
#pragma unroll
    for (int i = 0; i < 4; ++i)
#pragma unroll
      for (int j = 0; j < 4; ++j)
        acc[i][j] = __builtin_amdgcn_mfma_f32_16x16x32_f16(af[i], bf[j], acc[i][j], 0, 0, 0);
  }
#pragma unroll
  for (int j = 0; j < 4; ++j) {
    int n = bn0 + wn + 16 * j + mrow;
    float bj = bias[n];
#pragma unroll
    for (int i = 0; i < 4; ++i) {
#pragma unroll
      for (int r = 0; r < 4; ++r) {
        long m = bm0 + wm + 16 * i + quad * 4 + r;
        float v = acc[i][j][r] + bj;
        if (relu) v = fmaxf(v, 0.f);
        C[m * (long)ldC + n] = (_Float16)v;
      }
    }
  }
}

// ---------------- MFMA fp16 GEMM (256x128 tile)
__global__ __launch_bounds__(256, 2) void gemm_2(
    const _Float16* __restrict__ A, const _Float16* __restrict__ Bt,
    const float* __restrict__ bias, _Float16* __restrict__ C,
    int M, int N, int K, int ldC, int relu)
{
  __shared__ _Float16 As[256 * 32];
  __shared__ _Float16 Bs[128 * 32];
  int tid = threadIdx.x;
  int lane = tid & 63, wave = tid >> 6;
  long bm0 = (long)blockIdx.y * 256;
  int bn0 = blockIdx.x * 128;
  int srow = lane >> 2;
  int scol = (lane & 3) * 8;
  const _Float16* aA[4];
  _Float16* lA[4];
#pragma unroll
  for (int it = 0; it < 4; ++it) {
    aA[it] = A + (bm0 + wave * 64 + it * 16 + srow) * (long)K + scol;
    lA[it] = As + (wave * 64 + it * 16) * 32;
  }
  const _Float16* aB[2];
  _Float16* lB[2];
#pragma unroll
  for (int it = 0; it < 2; ++it) {
    aB[it] = Bt + (bn0 + it * 64 + wave * 16 + srow) * (long)K + scol;
    lB[it] = Bs + (it * 64 + wave * 16) * 32;
  }
  int mrow = lane & 15, quad = lane >> 4;
  floatx4 acc[4][8];
#pragma unroll
  for (int i = 0; i < 4; ++i)
#pragma unroll
    for (int j = 0; j < 8; ++j) acc[i][j] = (floatx4){0.f, 0.f, 0.f, 0.f};

  for (int kt = 0; kt < K; kt += 32) {
    __syncthreads();
#pragma unroll
    for (int it = 0; it < 4; ++it) gl_lds16(aA[it] + kt, lA[it]);
#pragma unroll
    for (int it = 0; it < 2; ++it) gl_lds16(aB[it] + kt, lB[it]);
    __syncthreads();
    half8 af[4], bf[8];
#pragma unroll
    for (int i = 0; i < 4; ++i)
      af[i] = *(const half8*)&As[(wave * 64 + 16 * i + mrow) * 32 + quad * 8];
#pragma unroll
    for (int j = 0; j < 8; ++j)
      bf[j] = *(const half8*)&Bs[(16 * j + mrow) * 32 + quad * 8];
#pragma unroll
    for (int i = 0; i < 4; ++i)
#pragma unroll
      for (int j = 0; j < 8; ++j)
        acc[i][j] = __builtin_amdgcn_mfma_f32_16x16x32_f16(af[i], bf[j], acc[i][j], 0, 0, 0);
  }
#pragma unroll
  for (int j = 0; j < 8; ++j) {
    int n = bn0 + 16 * j + mrow;
    float bj = bias[n];
#pragma unroll
    for (int i = 0; i < 4; ++i) {
#pragma unroll
      for (int r = 0; r < 4; ++r) {
        long m = bm0 + wave * 64 + 16 * i + quad * 4 + r;
        float v = acc[i][j][r] + bj;
        if (relu) v = fmaxf(v, 0.f);
        C[m * (long)ldC + n] = (_Float16)v;
      }
    }
  }
}

// ---------------- MFMA GEMM + bias + residual + LayerNorm, N fixed = 512.
// Block = 64 rows x 512 cols, 4 waves (wave = 16 rows x 512 cols, acc[32]).
// out[row0+m] = LN( A[m]@Bt^T + bias + res[(row0+m)&bmask] ) * g + b   (fp16 out)
// res is fp16 (resf32=0) or fp32 (resf32=1). K % 32 == 0, M % 64 == 0.
__global__ __launch_bounds__(256, 2) void gemm_ln(
    const _Float16* __restrict__ A, const _Float16* __restrict__ Bt,
    const float* __restrict__ bias, const void* __restrict__ res, int resf32,
    long row0, long bmask, const float* __restrict__ g, const float* __restrict__ b,
    _Float16* __restrict__ out, int M, int K)
{
  __shared__ _Float16 SH[33280];            // 65 KB: staging (36 KB) then epilogue (overlaid)
  _Float16* As = SH;                        // 64 x 32
  _Float16* Bs = SH + 2048;                 // 512 x 32
  int tid = threadIdx.x;
  int lane = tid & 63, wave = tid >> 6;
  int ll = lane & 15, quad = lane >> 4;
  long bm0 = (long)blockIdx.x * 64;
  int srow = lane >> 2, scol = (lane & 3) * 8;
  const _Float16* aA = A + (bm0 + wave * 16 + srow) * (long)K + scol;
  _Float16* lA = As + (wave * 16) * 32;
  const _Float16* aB[8];
  _Float16* lB[8];
#pragma unroll
  for (int t = 0; t < 8; ++t) {
    int br = wave * 128 + t * 16;
    aB[t] = Bt + (br + srow) * (long)K + scol;
    lB[t] = Bs + br * 32;
  }
  floatx4 acc[32];
#pragma unroll
  for (int j = 0; j < 32; ++j) acc[j] = (floatx4){0.f, 0.f, 0.f, 0.f};

  for (int kt = 0; kt < K; kt += 32) {
    __syncthreads();
    gl_lds16(aA + kt, lA);
#pragma unroll
    for (int t = 0; t < 8; ++t) gl_lds16(aB[t] + kt, lB[t]);
    __syncthreads();
    half8 af = *(const half8*)&As[(wave * 16 + ll) * 32 + quad * 8];
#pragma unroll
    for (int j = 0; j < 32; ++j) {
      half8 bf = *(const half8*)&Bs[(j * 16 + ll) * 32 + quad * 8];
      acc[j] = __builtin_amdgcn_mfma_f32_16x16x32_f16(af, bf, acc[j], 0, 0, 0);
    }
  }
  // bias
#pragma unroll
  for (int j = 0; j < 32; ++j) {
    float bv = bias[j * 16 + ll];
#pragma unroll
    for (int r = 0; r < 4; ++r) acc[j][r] += bv;
  }
  __syncthreads();                          // all waves done reading staging region
  // transpose to LDS fp16: wave region 16 rows x 512 cols (stride 520)
  _Float16* Ep = SH + wave * 8320;
#pragma unroll
  for (int j = 0; j < 32; ++j)
#pragma unroll
    for (int r = 0; r < 4; ++r)
      Ep[(quad * 4 + r) * 520 + j * 16 + ll] = (_Float16)acc[j][r];
  __syncthreads();
  // per-row LN: 4 lanes per row, 128 cols each
  int lr = lane >> 2, cg = lane & 3;
  long orow = row0 + bm0 + wave * 16 + lr;
  long rrow = orow & bmask;
  const _Float16* eprow = Ep + lr * 520 + cg * 128;
  const float* resf = (const float*)res;
  const _Float16* resh = (const _Float16*)res;
  long rbase = rrow * 512 + cg * 128;
  float s = 0.f, sq = 0.f;
#pragma unroll
  for (int c = 0; c < 16; ++c) {
    half8 hv = *(const half8*)&eprow[c * 8];
    float vv[8];
    if (resf32) {
      float4 f0 = *(const float4*)&resf[rbase + c * 8];
      float4 f1 = *(const float4*)&resf[rbase + c * 8 + 4];
      float fr[8] = {f0.x, f0.y, f0.z, f0.w, f1.x, f1.y, f1.z, f1.w};
#pragma unroll
      for (int i = 0; i < 8; ++i) vv[i] = (float)hv[i] + fr[i];
    } else {
      half8 rv = *(const half8*)&resh[rbase + c * 8];
#pragma unroll
      for (int i = 0; i < 8; ++i) vv[i] = (float)hv[i] + (float)rv[i];
    }
#pragma unroll
    for (int i = 0; i < 8; ++i) { s += vv[i]; sq += vv[i] * vv[i]; }
  }
  s += __shfl_xor(s, 1); s += __shfl_xor(s, 2);
  sq += __shfl_xor(sq, 1); sq += __shfl_xor(sq, 2);
  float mean = s * (1.f / 512.f);
  float var = sq * (1.f / 512.f) - mean * mean;
  float rst = rsqrtf(var + 1e-6f);
  long obase = orow * 512 + cg * 128;
#pragma unroll
  for (int c = 0; c < 16; ++c) {
    half8 hv = *(const half8*)&eprow[c * 8];
    float vv[8];
    if (resf32) {
      float4 f0 = *(const float4*)&resf[rbase + c * 8];
      float4 f1 = *(const float4*)&resf[rbase + c * 8 + 4];
      float fr[8] = {f0.x, f0.y, f0.z, f0.w, f1.x, f1.y, f1.z, f1.w};
#pragma unroll
      for (int i = 0; i < 8; ++i) vv[i] = (float)hv[i] + fr[i];
    } else {
      half8 rv = *(const half8*)&resh[rbase + c * 8];
#pragma unroll
      for (int i = 0; i < 8; ++i) vv[i] = (float)hv[i] + (float)rv[i];
    }
    int col = cg * 128 + c * 8;
    float4 g0 = *(const float4*)&g[col], g1 = *(const float4*)&g[col + 4];
    float4 b0 = *(const float4*)&b[col], b1 = *(const float4*)&b[col + 4];
    float gg[8] = {g0.x, g0.y, g0.z, g0.w, g1.x, g1.y, g1.z, g1.w};
    float bb[8] = {b0.x, b0.y, b0.z, b0.w, b1.x, b1.y, b1.z, b1.w};
    half8 o;
#pragma unroll
    for (int i = 0; i < 8; ++i) o[i] = (_Float16)((vv[i] - mean) * rst * gg[i] + bb[i]);
    *(half8*)&out[obase + c * 8] = o;
  }
}

// ---------------- MFMA fused attention (unchanged)
__global__ __launch_bounds__(256) void attn_h(
    const _Float16* __restrict__ Qp, int qs,
    const _Float16* __restrict__ Kp, const _Float16* __restrict__ Vp, int ks,
    _Float16* __restrict__ Op, int mode_ca, int l0, int rb0)
{
  __shared__ _Float16 KV[128 * 72];
  __shared__ _Float16 Ps[128 * 136];
  int tid = threadIdx.x;
  int lane = tid & 63, wave = tid >> 6;
  int ll = lane & 15, quad = lane >> 4;
  int idx = blockIdx.x;
  int n = idx & 7;
  int rl = idx >> 3;
  long obase = (long)rl * 128 * 512 + n * 64;
  long qoff, koff;
  if (!mode_ca) {
    qoff = (long)rl * 128 * qs + n * 64;
    koff = (long)rl * 128 * ks + n * 64;
  } else {
    int g = rb0 + rl;
    int a = g >> 5;
    int qblk = l0 ? (g & 31) : rl;
    qoff = (long)qblk * 128 * qs + n * 64;
    koff = (long)a * 128 * ks + n * 64;
  }
#pragma unroll
  for (int it = 0; it < 4; ++it) {
    int e = tid + it * 256;
    int r = e >> 3, c = (e & 7) * 8;
    *(half8*)&KV[r * 72 + c] = *(const half8*)&Kp[koff + (long)r * ks + c];
  }
  half8 aQ[2][2];
#pragma unroll
  for (int i = 0; i < 2; ++i)
#pragma unroll
    for (int k2 = 0; k2 < 2; ++k2)
      aQ[i][k2] = *(const half8*)&Qp[qoff + (long)(wave * 32 + i * 16 + ll) * qs
                                     + quad * 8 + k2 * 32];
  __syncthreads();
  floatx4 accS[2][8];
#pragma unroll
  for (int i = 0; i < 2; ++i)
#pragma unroll
    for (int j = 0; j < 8; ++j) accS[i][j] = (floatx4){0.f, 0.f, 0.f, 0.f};
#pragma unroll
  for (int k2 = 0; k2 < 2; ++k2) {
#pragma unroll
    for (int j = 0; j < 8; ++j) {
      half8 bK = *(const half8*)&KV[(j * 16 + ll) * 72 + quad * 8 + k2 * 32];
      accS[0][j] = __builtin_amdgcn_mfma_f32_16x16x32_f16(aQ[0][k2], bK, accS[0][j], 0, 0, 0);
      accS[1][j] = __builtin_amdgcn_mfma_f32_16x16x32_f16(aQ[1][k2], bK, accS[1][j], 0, 0, 0);
    }
  }
  float rinv[2][4];
#pragma unroll
  for (int i = 0; i < 2; ++i) {
#pragma unroll
    for (int r = 0; r < 4; ++r) {
      float mx = -1e30f;
#pragma unroll
      for (int j = 0; j < 8; ++j) {
        accS[i][j][r] *= 0.125f;
        mx = fmaxf(mx, accS[i][j][r]);
      }
#pragma unroll
      for (int off = 1; off < 16; off <<= 1) mx = fmaxf(mx, __shfl_xor(mx, off));
      float s = 0.f;
#pragma unroll
      for (int j = 0; j < 8; ++j) {
        float e = __expf(accS[i][j][r] - mx);
        accS[i][j][r] = e;
        s += e;
      }
#pragma unroll
      for (int off = 1; off < 16; off <<= 1) s += __shfl_xor(s, off);
      rinv[i][r] = 1.f / s;
      int prow = wave * 32 + i * 16 + quad * 4 + r;
#pragma unroll
      for (int j = 0; j < 8; ++j)
        Ps[prow * 136 + j * 16 + ll] = (_Float16)accS[i][j][r];
    }
  }
  __syncthreads();
#pragma unroll
  for (int it = 0; it < 4; ++it) {
    int e = tid + it * 256;
    int vr = e >> 3, c = (e & 7) * 8;
    half8 v = *(const half8*)&Vp[koff + (long)vr * ks + c];
#pragma unroll
    for (int j = 0; j < 8; ++j) KV[(c + j) * 132 + vr] = v[j];
  }
  __syncthreads();
  floatx4 accO[2][4];
#pragma unroll
  for (int i = 0; i < 2; ++i)
#pragma unroll
    for (int j = 0; j < 4; ++j) accO[i][j] = (floatx4){0.f, 0.f, 0.f, 0.f};
#pragma unroll
  for (int k4 = 0; k4 < 4; ++k4) {
    half8 aP[2];
#pragma unroll
    for (int i = 0; i < 2; ++i)
      aP[i] = *(const half8*)&Ps[(wave * 32 + i * 16 + ll) * 136 + quad * 8 + k4 * 32];
#pragma unroll
    for (int jh = 0; jh < 4; ++jh) {
      int vb = (jh * 16 + ll) * 132 + quad * 8 + k4 * 32;
      half4 v0 = *(const half4*)&KV[vb];
      half4 v1 = *(const half4*)&KV[vb + 4];
      half8 bV = __builtin_shufflevector(v0, v1, 0, 1, 2, 3, 4, 5, 6, 7);
      accO[0][jh] = __builtin_amdgcn_mfma_f32_16x16x32_f16(aP[0], bV, accO[0][jh], 0, 0, 0);
      accO[1][jh] = __builtin_amdgcn_mfma_f32_16x16x32_f16(aP[1], bV, accO[1][jh], 0, 0, 0);
    }
  }
#pragma unroll
  for (int i = 0; i < 2; ++i)
#pragma unroll
    for (int jh = 0; jh < 4; ++jh)
#pragma unroll
      for (int r = 0; r < 4; ++r) {
        int m = wave * 32 + i * 16 + quad * 4 + r;
        Op[obase + (long)m * 512 + jh * 16 + ll] = (_Float16)(accO[i][jh][r] * rinv[i][r]);
      }
}

// ---------------- standalone LayerNorm (final LN only)
__global__ __launch_bounds__(256) void ln_h(
    const _Float16* __restrict__ xin, _Float16* __restrict__ out,
    const float* __restrict__ g, const float* __restrict__ bt)
{
  int row = blockIdx.x * 4 + (threadIdx.x >> 6);
  int lane = threadIdx.x & 63;
  long xr = (long)row * 512 + lane * 8;
  half8 h = *(const half8*)&xin[xr];
  float v[8];
#pragma unroll
  for (int i = 0; i < 8; ++i) v[i] = (float)h[i];
  float s = 0.f, sq = 0.f;
#pragma unroll
  for (int i = 0; i < 8; ++i) { s += v[i]; sq += v[i] * v[i]; }
#pragma unroll
  for (int off = 1; off < 64; off <<= 1) {
    s += __shfl_xor(s, off);
    sq += __shfl_xor(sq, off);
  }
  float mean = s * (1.f / 512.f);
  float var = sq * (1.f / 512.f) - mean * mean;
  float rst = rsqrtf(var + 1e-6f);
  int c = lane * 8;
  float4 g0 = *(const float4*)&g[c], g1 = *(const float4*)&g[c + 4];
  float4 b0 = *(const float4*)&bt[c], b1 = *(const float4*)&bt[c + 4];
  float gg[8] = {g0.x, g0.y, g0.z, g0.w, g1.x, g1.y, g1.z, g1.w};
  float bb[8] = {b0.x, b0.y, b0.z, b0.w, b1.x, b1.y, b1.z, b1.w};
  half8 o;
#pragma unroll
  for (int i = 0; i < 8; ++i) o[i] = (_Float16)((v[i] - mean) * rst * gg[i] + bb[i]);
  *(half8*)&out[xr] = o;
}

// ---------------- batched 512x512 transpose-convert (12 weights in one launch)
__global__ __launch_bounds__(256) void tconv512(
    const float* __restrict__ w0, const float* __restrict__ w1,
    const float* __restrict__ w2, const float* __restrict__ w3,
    const float* __restrict__ w4, const float* __restrict__ w5,
    _Float16* __restrict__ Wh)
{
  __shared__ float T[64][65];
  int z = blockIdx.z;
  int t = z >> 1, l = z & 1;
  const float* src;
  long off;
  switch (t) {
    case 0: src = w0; off = 0; break;
    case 1: src = w1; off = 262144; break;
    case 2: src = w2; off = 524288; break;
    case 3: src = w3; off = 1048576; break;
    case 4: src = w4; off = 1310720; break;
    default: src = w5; off = 1572864; break;
  }
  src += (long)l * 262144;
  _Float16* out = Wh + (long)l * 4194304 + off;
  int tx = threadIdx.x & 63, tg = threadIdx.x >> 6;
  int r0 = blockIdx.y * 64, c0 = blockIdx.x * 64;
#pragma unroll
  for (int i = 0; i < 16; ++i)
    T[tg + 4 * i][tx] = src[(long)(r0 + tg + 4 * i) * 512 + c0 + tx];
  __syncthreads();
#pragma unroll
  for (int i = 0; i < 16; ++i)
    out[(long)(c0 + tg + 4 * i) * 512 + r0 + tx] = (_Float16)T[tx][tg + 4 * i];
}

// ---------------- layered transpose-convert for FFN weights
__global__ __launch_bounds__(256) void tconvL(const float* __restrict__ in,
                                              _Float16* __restrict__ out, int Rr, int Cc,
                                              long ils, long ols)
{
  __shared__ float T[64][65];
  in += (long)blockIdx.z * ils;
  out += (long)blockIdx.z * ols;
  int tx = threadIdx.x & 63, tg = threadIdx.x >> 6;
  int r0 = blockIdx.y * 64, c0 = blockIdx.x * 64;
#pragma unroll
  for (int i = 0; i < 16; ++i)
    T[tg + 4 * i][tx] = in[(long)(r0 + tg + 4 * i) * Cc + c0 + tx];
  __syncthreads();
#pragma unroll
  for (int i = 0; i < 16; ++i)
    out[(long)(c0 + tg + 4 * i) * Rr + r0 + tx] = (_Float16)T[tx][tg + 4 * i];
}

// ---------------- batched wo conversion: z = s*2 + l, s: 0=sa(off 786432), 1=ca(1835008)
__global__ void woconvB(const float* __restrict__ sa_wo, const float* __restrict__ ca_wo,
                        _Float16* __restrict__ Wh)
{
  int z = blockIdx.y;
  int s = z >> 1, l = z & 1;
  const float* wo = (s ? ca_wo : sa_wo) + (long)l * 262144;
  _Float16* out = Wh + (long)l * 4194304 + (s ? 1835008 : 786432);
  int o = blockIdx.x * 256 + threadIdx.x;  // 262144
  int d = o >> 9;
  int nh = o & 511;
  int n = nh >> 6, h = nh & 63;
  out[o] = (_Float16)wo[((long)(n << 9) + d) * 64 + h];
}

// ---------------- pack all biases in one launch (5120 elems, 10 regions of 512)
__global__ void packbias(const float* __restrict__ sa_bq, const float* __restrict__ sa_bk,
                         const float* __restrict__ sa_bv, const float* __restrict__ ca_bk,
                         const float* __restrict__ ca_bv, float* __restrict__ Bqkv,
                         float* __restrict__ Bkv)
{
  int i = blockIdx.x * 256 + threadIdx.x;
  if (i >= 5120) return;
  int reg = i >> 9, idx = i & 511;
  int l = reg / 5, r = reg % 5;
  int lo = l * 512;
  switch (r) {
    case 0: Bqkv[l * 1536 + idx] = sa_bq[lo + idx]; break;
    case 1: Bqkv[l * 1536 + 512 + idx] = sa_bk[lo + idx]; break;
    case 2: Bqkv[l * 1536 + 1024 + idx] = sa_bv[lo + idx]; break;
    case 3: Bkv[l * 1024 + idx] = ca_bk[lo + idx]; break;
    default: Bkv[l * 1024 + 512 + idx] = ca_bv[lo + idx]; break;
  }
}

// ---------------- fused fp32->fp16 for c and q
__global__ void f2h2(const float* __restrict__ a, _Float16* __restrict__ oa, long na,
                     const float* __restrict__ bsrc, _Float16* __restrict__ ob, long nb)
{
  long i = blockIdx.x * 256L + threadIdx.x;
  if (i < na) oa[i] = (_Float16)a[i];
  else if (i < na + nb) ob[i - na] = (_Float16)bsrc[i - na];
}

// ---------------- mean over tokens 1..127 -> [ab, 512]
__global__ void pool_h(const _Float16* __restrict__ X, float* __restrict__ P)
{
  int ab = blockIdx.x;
  for (int dd = threadIdx.x; dd < 512; dd += 256) {
    const _Float16* base = X + (long)ab * 65536 + dd;
    float s = 0.f;
    for (int t = 1; t < 128; ++t) s += (float)base[t * 512];
    P[ab * 512 + dd] = s * (1.f / 127.f);
  }
}

__global__ void pool_f(const float* __restrict__ X, float* __restrict__ P)
{
  int ab = blockIdx.x;
  for (int dd = threadIdx.x; dd < 512; dd += 256) {
    const float* base = X + (long)ab * 65536 + dd;
    float s = 0.f;
    for (int t = 1; t < 128; ++t) s += base[t * 512];
    P[ab * 512 + dd] = s * (1.f / 127.f);
  }
}

__global__ void featq_kernel(const float* __restrict__ QP, const float* __restrict__ W,
                             const float* __restrict__ bias, float* __restrict__ QN)
{
  int a = blockIdx.x;
  int f = threadIdx.x;
  float acc = bias[f];
  const float* xr = QP + a * 512;
  for (int d = 0; d < 512; ++d) acc += xr[d] * W[d * 256 + f];
  __shared__ float red[256];
  red[f] = acc * acc;
  __syncthreads();
  for (int s = 128; s > 0; s >>= 1) {
    if (f < s) red[f] += red[f + s];
    __syncthreads();
  }
  float rn = rsqrtf(fmaxf(red[0], 1e-12f));
  QN[a * 256 + f] = acc * rn;
}

__global__ void featc_kernel(const float* __restrict__ CP, const float* __restrict__ W,
                             const float* __restrict__ bias, const float* __restrict__ QN,
                             float* __restrict__ out)
{
  int ab = blockIdx.x;
  int f = threadIdx.x;
  float acc = bias[f];
  const float* xr = CP + ab * 512;
  for (int d = 0; d < 512; ++d) acc += xr[d] * W[d * 256 + f];
  __shared__ float red[256];
  red[f] = acc * acc;
  __syncthreads();
  for (int s = 128; s > 0; s >>= 1) {
    if (f < s) red[f] += red[f + s];
    __syncthreads();
  }
  float rn = rsqrtf(fmaxf(red[0], 1e-12f));
  float v = acc * rn * QN[(ab >> 5) * 256 + f];
  __syncthreads();
  red[f] = v;
  __syncthreads();
  for (int s = 128; s > 0; s >>= 1) {
    if (f < s) red[f] += red[f + s];
    __syncthreads();
  }
  if (f == 0) out[ab] = red[0];
}

extern "C" void kernel_launch(void* const* d_in, const int* in_sizes, int n_in,
                              void* d_out, int out_size, void* d_ws, size_t ws_size,
                              hipStream_t stream)
{
  (void)in_sizes; (void)n_in; (void)out_size;
  const float* c_in  = (const float*)d_in[0];
  const float* q_in  = (const float*)d_in[1];
  const float* sa_wq = (const float*)d_in[2];
  const float* sa_bq = (const float*)d_in[3];
  const float* sa_wk = (const float*)d_in[4];
  const float* sa_bk = (const float*)d_in[5];
  const float* sa_wv = (const float*)d_in[6];
  const float* sa_bv = (const float*)d_in[7];
  const float* sa_wo = (const float*)d_in[8];
  const float* sa_bo = (const float*)d_in[9];
  const float* ca_wq = (const float*)d_in[10];
  const float* ca_bq = (const float*)d_in[11];
  const float* ca_wk = (const float*)d_in[12];
  const float* ca_bk = (const float*)d_in[13];
  const float* ca_wv = (const float*)d_in[14];
  const float* ca_bv = (const float*)d_in[15];
  const float* ca_wo = (const float*)d_in[16];
  const float* ca_bo = (const float*)d_in[17];
  const float* ln1_g = (const float*)d_in[18];
  const float* ln1_b = (const float*)d_in[19];
  const float* ln2_g = (const float*)d_in[20];
  const float* ln2_b = (const float*)d_in[21];
  const float* ln3_g = (const float*)d_in[22];
  const float* ln3_b = (const float*)d_in[23];
  const float* ffn_w1 = (const float*)d_in[24];
  const float* ffn_b1 = (const float*)d_in[25];
  const float* ffn_w2 = (const float*)d_in[26];
  const float* ffn_b2 = (const float*)d_in[27];
  const float* lnf_g  = (const float*)d_in[28];
  const float* lnf_b  = (const float*)d_in[29];
  const float* feat_wq = (const float*)d_in[30];
  const float* feat_bq = (const float*)d_in[31];
  const float* feat_wc = (const float*)d_in[32];
  const float* feat_bc = (const float*)d_in[33];

  // ---- workspace layout
  char* p = (char*)d_ws;
  _Float16* Xh  = (_Float16*)p;  p += 33554432;  // 32768 x 512 fp16 residual stream
  _Float16* Xsh = (_Float16*)p;  p += 4194304;   //  4096 x 512 fp16 (layer-0 x)
  _Float16* Wh  = (_Float16*)p;  p += 16777216;  // fp16 weight arena (2 layers)
  _Float16* qh  = (_Float16*)p;  p += 1048576;   //  1024 x 512 fp16
  _Float16* KV0 = (_Float16*)p;  p += 2097152;   //  1024 x 1024 fp16 (K|V)
  float*    Bqkv = (float*)p;    p += 12288;
  float*    Bkv  = (float*)p;    p += 8192;
  float*    CP  = (float*)p;     p += 524288;
  float*    QP  = (float*)p;     p += 16384;
  float*    QN  = (float*)p;     p += 8192;
  const size_t fixed_b = (size_t)(p - (char*)d_ws);
  long R = 4096;
  if (ws_size >= fixed_b + 5120UL * 32768) R = 32768;
  else if (ws_size >= fixed_b + 5120UL * 16384) R = 16384;
  else if (ws_size >= fixed_b + 5120UL * 8192) R = 8192;
  _Float16* QKVc = (_Float16*)p; p += R * 3072;  // [R][1536]
  _Float16* Oc   = (_Float16*)p; p += R * 1024;  // [R][512]
  _Float16* Hb = QKVc;            // FFN hidden [R/2][2048] aliases QKVc
  const long Rh = R / 2;
  const long NEG1 = ~0L;

  // ---- prep (6 launches)
  f2h2<<<10240, 256, 0, stream>>>(c_in, Xsh, 2097152, q_in, qh, 524288);
  tconv512<<<dim3(8, 8, 12), 256, 0, stream>>>(sa_wq, sa_wk, sa_wv, ca_wq, ca_wk, ca_wv, Wh);
  woconvB<<<dim3(1024, 4), 256, 0, stream>>>(sa_wo, ca_wo, Wh);
  tconvL<<<dim3(32, 8, 2), 256, 0, stream>>>(ffn_w1, Wh + 2097152, 512, 2048, 1048576, 4194304);
  tconvL<<<dim3(8, 32, 2), 256, 0, stream>>>(ffn_w2, Wh + 3145728, 2048, 512, 1048576, 4194304);
  packbias<<<20, 256, 0, stream>>>(sa_bq, sa_bk, sa_bv, ca_bk, ca_bv, Bqkv, Bkv);

  // =================== layer 0 (x rows = 4096) ===================
  {
    _Float16* Wl = Wh;
    gemm_h<<<dim3(12, 32), 256, 0, stream>>>(Xsh, Wl + 0, Bqkv, QKVc, 4096, 1536, 512, 1536, 0);
    attn_h<<<256, 256, 0, stream>>>(QKVc, 1536, QKVc + 512, QKVc + 1024, 1536, Oc, 0, 0, 0);
    gemm_ln<<<64, 256, 0, stream>>>(Oc, Wl + 786432, sa_bo, c_in, 1, 0L, NEG1,
                                    ln1_g, ln1_b, Xsh, 4096, 512);
    gemm_h<<<dim3(4, 32), 256, 0, stream>>>(Xsh, Wl + 1048576, ca_bq, QKVc, 4096, 512, 512, 1536, 0);
    gemm_h<<<dim3(8, 8), 256, 0, stream>>>(qh, Wl + 1310720, Bkv, KV0, 1024, 1024, 512, 1024, 0);
    for (long c = 0; c < 32768; c += R) {
      attn_h<<<(R / 128) * 8, 256, 0, stream>>>(QKVc, 1536, KV0, KV0 + 512, 1024, Oc,
                                                1, 1, (int)(c / 128));
      gemm_ln<<<R / 64, 256, 0, stream>>>(Oc, Wl + 1835008, ca_bo, Xsh, 0, c, 4095L,
                                          ln2_g, ln2_b, Xh, (int)R, 512);
      for (long s = 0; s < R; s += Rh) {
        gemm_2<<<dim3(16, Rh / 256), 256, 0, stream>>>(Xh + (c + s) * 512, Wl + 2097152,
                                                       ffn_b1, Hb, (int)Rh, 2048, 512, 2048, 1);
        gemm_ln<<<Rh / 64, 256, 0, stream>>>(Hb, Wl + 3145728, ffn_b2, Xh, 0, c + s, NEG1,
                                             ln3_g, ln3_b, Xh, (int)Rh, 2048);
      }
    }
  }
  // =================== layer 1 (x rows = 32768) ===================
  {
    _Float16* Wl = Wh + 4194304;
    gemm_h<<<dim3(8, 8), 256, 0, stream>>>(qh, Wl + 1310720, Bkv + 1024, KV0, 1024, 1024, 512, 1024, 0);
    for (long c = 0; c < 32768; c += R) {
      _Float16* Xhc = Xh + c * 512;
      gemm_2<<<dim3(12, R / 256), 256, 0, stream>>>(Xhc, Wl + 0, Bqkv + 1536, QKVc,
                                                    (int)R, 1536, 512, 1536, 0);
      attn_h<<<(R / 128) * 8, 256, 0, stream>>>(QKVc, 1536, QKVc + 512, QKVc + 1024, 1536,
                                                Oc, 0, 0, 0);
      gemm_ln<<<R / 64, 256, 0, stream>>>(Oc, Wl + 786432, sa_bo + 512, Xh, 0, c, NEG1,
                                          ln1_g + 512, ln1_b + 512, Xh, (int)R, 512);
      gemm_2<<<dim3(4, R / 256), 256, 0, stream>>>(Xhc, Wl + 1048576, ca_bq + 512, QKVc,
                                                   (int)R, 512, 512, 1536, 0);
      attn_h<<<(R / 128) * 8, 256, 0, stream>>>(QKVc, 1536, KV0, KV0 + 512, 1024, Oc,
                                                1, 0, (int)(c / 128));
      gemm_ln<<<R / 64, 256, 0, stream>>>(Oc, Wl + 1835008, ca_bo + 512, Xh, 0, c, NEG1,
                                          ln2_g + 512, ln2_b + 512, Xh, (int)R, 512);
      for (long s = 0; s < R; s += Rh) {
        gemm_2<<<dim3(16, Rh / 256), 256, 0, stream>>>(Xh + (c + s) * 512, Wl + 2097152,
                                                       ffn_b1 + 2048, Hb, (int)Rh, 2048, 512, 2048, 1);
        gemm_ln<<<Rh / 64, 256, 0, stream>>>(Hb, Wl + 3145728, ffn_b2 + 512, Xh, 0, c + s, NEG1,
                                             ln3_g + 512, ln3_b + 512, Xh, (int)Rh, 2048);
      }
    }
  }
  // =================== final LN + pooling + features + cosine ===================
  ln_h<<<8192, 256, 0, stream>>>(Xh, Xh, lnf_g, lnf_b);
  pool_h<<<256, 256, 0, stream>>>(Xh, CP);
  pool_f<<<8, 256, 0, stream>>>(q_in, QP);
  featq_kernel<<<8, 256, 0, stream>>>(QP, feat_wq, feat_bq, QN);
  featc_kernel<<<256, 256, 0, stream>>>(CP, feat_wc, feat_bc, QN, (float*)d_out);
}

// Round 9
// 1172.607 us; speedup vs baseline: 1.2959x; 1.2959x over previous
//
#include <hip/hip_runtime.h>

using half4  = __attribute__((ext_vector_type(4))) _Float16;
using half8  = __attribute__((ext_vector_type(8))) _Float16;
using floatx4 = __attribute__((ext_vector_type(4))) float;

__device__ __forceinline__ void gl_lds16(const _Float16* g, _Float16* l)
{
  __builtin_amdgcn_global_load_lds(
      (const __attribute__((address_space(1))) void*)g,
      (__attribute__((address_space(3))) void*)l, 16, 0, 0);
}

// XOR-swizzled LDS layout for BK=32 tiles (stride 32 halfs = 64 B):
// LDS seg s of row r holds global seg s ^ ((r>>1)&3)  (seg = 16 B).
// Staging keeps dest = base + lane*16 (required by global_load_lds); the
// global SOURCE column is permuted per lane. Readers xor the same selector.
// Bank groups become (r&1, quad^((r>>1)&3)) -> only 2-way aliasing (free).

// ---------------- MFMA fp16 GEMM (128x128 tile): C = A @ Bt^T + bias
__global__ __launch_bounds__(256) void gemm_h(
    const _Float16* __restrict__ A, const _Float16* __restrict__ Bt,
    const float* __restrict__ bias, _Float16* __restrict__ C,
    int M, int N, int K, int ldC, int relu)
{
  __shared__ _Float16 As[128 * 32];
  __shared__ _Float16 Bs[128 * 32];
  int tid = threadIdx.x;
  int lane = tid & 63, wave = tid >> 6;
  long bm0 = (long)blockIdx.y * 128;
  int bn0 = blockIdx.x * 128;
  int wm = (wave & 1) * 64, wn = (wave >> 1) * 64;
  int srow = wave * 16 + (lane >> 2);
  int scol = (((lane & 3) ^ ((lane >> 3) & 3)) * 8);   // swizzled global source col
  const _Float16* aA0 = A + (bm0 + srow) * (long)K + scol;
  const _Float16* aA1 = aA0 + 64 * (long)K;
  const _Float16* aB0 = Bt + (bn0 + srow) * (long)K + scol;
  const _Float16* aB1 = aB0 + 64 * (long)K;
  _Float16* lA0 = As + wave * 512;
  _Float16* lA1 = As + 2048 + wave * 512;
  _Float16* lB0 = Bs + wave * 512;
  _Float16* lB1 = Bs + 2048 + wave * 512;
  int mrow = lane & 15, quad = lane >> 4;
  int cofs = (quad ^ ((mrow >> 1) & 3)) * 8;           // swizzled reader col
  floatx4 acc[4][4];
#pragma unroll
  for (int i = 0; i < 4; ++i)
#pragma unroll
    for (int j = 0; j < 4; ++j) acc[i][j] = (floatx4){0.f, 0.f, 0.f, 0.f};

  for (int kt = 0; kt < K; kt += 32) {
    __syncthreads();
    gl_lds16(aA0 + kt, lA0);
    gl_lds16(aA1 + kt, lA1);
    gl_lds16(aB0 + kt, lB0);
    gl_lds16(aB1 + kt, lB1);
    __syncthreads();
    half8 af[4], bf[4];
#pragma unroll
    for (int i = 0; i < 4; ++i)
      af[i] = *(const half8*)&As[(wm + 16 * i + mrow) * 32 + cofs];
#pragma unroll
    for (int j = 0; j < 4; ++j)
      bf[j] = *(const half8*)&Bs[(wn + 16 * j + mrow) * 32 + cofs];
#pragma unroll
    for (int i = 0; i < 4; ++i)
#pragma unroll
      for (int j = 0; j < 4; ++j)
        acc[i][j] = __builtin_amdgcn_mfma_f32_16x16x32_f16(af[i], bf[j], acc[i][j], 0, 0, 0);
  }
#pragma unroll
  for (int j = 0; j < 4; ++j) {
    int n = bn0 + wn + 16 * j + mrow;
    float bj = bias[n];
#pragma unroll
    for (int i = 0; i < 4; ++i) {
#pragma unroll
      for (int r = 0; r < 4; ++r) {
        long m = bm0 + wm + 16 * i + quad * 4 + r;
        float v = acc[i][j][r] + bj;
        if (relu) v = fmaxf(v, 0.f);
        C[m * (long)ldC + n] = (_Float16)v;
      }
    }
  }
}

// ---------------- MFMA fp16 GEMM (256x128 tile), swizzled
__global__ __launch_bounds__(256, 2) void gemm_2(
    const _Float16* __restrict__ A, const _Float16* __restrict__ Bt,
    const float* __restrict__ bias, _Float16* __restrict__ C,
    int M, int N, int K, int ldC, int relu)
{
  __shared__ _Float16 As[256 * 32];
  __shared__ _Float16 Bs[128 * 32];
  int tid = threadIdx.x;
  int lane = tid & 63, wave = tid >> 6;
  long bm0 = (long)blockIdx.y * 256;
  int bn0 = blockIdx.x * 128;
  int srow = lane >> 2;
  int scol = (((lane & 3) ^ ((lane >> 3) & 3)) * 8);   // swizzled global source col
  const _Float16* aA[4];
  _Float16* lA[4];
#pragma unroll
  for (int it = 0; it < 4; ++it) {
    aA[it] = A + (bm0 + wave * 64 + it * 16 + srow) * (long)K + scol;
    lA[it] = As + (wave * 64 + it * 16) * 32;
  }
  const _Float16* aB[2];
  _Float16* lB[2];
#pragma unroll
  for (int it = 0; it < 2; ++it) {
    aB[it] = Bt + (bn0 + it * 64 + wave * 16 + srow) * (long)K + scol;
    lB[it] = Bs + (it * 64 + wave * 16) * 32;
  }
  int mrow = lane & 15, quad = lane >> 4;
  int cofs = (quad ^ ((mrow >> 1) & 3)) * 8;
  floatx4 acc[4][8];
#pragma unroll
  for (int i = 0; i < 4; ++i)
#pragma unroll
    for (int j = 0; j < 8; ++j) acc[i][j] = (floatx4){0.f, 0.f, 0.f, 0.f};

  for (int kt = 0; kt < K; kt += 32) {
    __syncthreads();
#pragma unroll
    for (int it = 0; it < 4; ++it) gl_lds16(aA[it] + kt, lA[it]);
#pragma unroll
    for (int it = 0; it < 2; ++it) gl_lds16(aB[it] + kt, lB[it]);
    __syncthreads();
    half8 af[4], bf[8];
#pragma unroll
    for (int i = 0; i < 4; ++i)
      af[i] = *(const half8*)&As[(wave * 64 + 16 * i + mrow) * 32 + cofs];
#pragma unroll
    for (int j = 0; j < 8; ++j)
      bf[j] = *(const half8*)&Bs[(16 * j + mrow) * 32 + cofs];
#pragma unroll
    for (int i = 0; i < 4; ++i)
#pragma unroll
      for (int j = 0; j < 8; ++j)
        acc[i][j] = __builtin_amdgcn_mfma_f32_16x16x32_f16(af[i], bf[j], acc[i][j], 0, 0, 0);
  }
#pragma unroll
  for (int j = 0; j < 8; ++j) {
    int n = bn0 + 16 * j + mrow;
    float bj = bias[n];
#pragma unroll
    for (int i = 0; i < 4; ++i) {
#pragma unroll
      for (int r = 0; r < 4; ++r) {
        long m = bm0 + wave * 64 + 16 * i + quad * 4 + r;
        float v = acc[i][j][r] + bj;
        if (relu) v = fmaxf(v, 0.f);
        C[m * (long)ldC + n] = (_Float16)v;
      }
    }
  }
}

// ---------------- MFMA fused attention (unchanged from round 6/7)
__global__ __launch_bounds__(256) void attn_h(
    const _Float16* __restrict__ Qp, int qs,
    const _Float16* __restrict__ Kp, const _Float16* __restrict__ Vp, int ks,
    _Float16* __restrict__ Op, int mode_ca, int l0, int rb0)
{
  __shared__ _Float16 KV[128 * 72];
  __shared__ _Float16 Ps[128 * 136];
  int tid = threadIdx.x;
  int lane = tid & 63, wave = tid >> 6;
  int ll = lane & 15, quad = lane >> 4;
  int idx = blockIdx.x;
  int n = idx & 7;
  int rl = idx >> 3;
  long obase = (long)rl * 128 * 512 + n * 64;
  long qoff, koff;
  if (!mode_ca) {
    qoff = (long)rl * 128 * qs + n * 64;
    koff = (long)rl * 128 * ks + n * 64;
  } else {
    int g = rb0 + rl;
    int a = g >> 5;
    int qblk = l0 ? (g & 31) : rl;
    qoff = (long)qblk * 128 * qs + n * 64;
    koff = (long)a * 128 * ks + n * 64;
  }
#pragma unroll
  for (int it = 0; it < 4; ++it) {
    int e = tid + it * 256;
    int r = e >> 3, c = (e & 7) * 8;
    *(half8*)&KV[r * 72 + c] = *(const half8*)&Kp[koff + (long)r * ks + c];
  }
  half8 aQ[2][2];
#pragma unroll
  for (int i = 0; i < 2; ++i)
#pragma unroll
    for (int k2 = 0; k2 < 2; ++k2)
      aQ[i][k2] = *(const half8*)&Qp[qoff + (long)(wave * 32 + i * 16 + ll) * qs
                                     + quad * 8 + k2 * 32];
  __syncthreads();
  floatx4 accS[2][8];
#pragma unroll
  for (int i = 0; i < 2; ++i)
#pragma unroll
    for (int j = 0; j < 8; ++j) accS[i][j] = (floatx4){0.f, 0.f, 0.f, 0.f};
#pragma unroll
  for (int k2 = 0; k2 < 2; ++k2) {
#pragma unroll
    for (int j = 0; j < 8; ++j) {
      half8 bK = *(const half8*)&KV[(j * 16 + ll) * 72 + quad * 8 + k2 * 32];
      accS[0][j] = __builtin_amdgcn_mfma_f32_16x16x32_f16(aQ[0][k2], bK, accS[0][j], 0, 0, 0);
      accS[1][j] = __builtin_amdgcn_mfma_f32_16x16x32_f16(aQ[1][k2], bK, accS[1][j], 0, 0, 0);
    }
  }
  float rinv[2][4];
#pragma unroll
  for (int i = 0; i < 2; ++i) {
#pragma unroll
    for (int r = 0; r < 4; ++r) {
      float mx = -1e30f;
#pragma unroll
      for (int j = 0; j < 8; ++j) {
        accS[i][j][r] *= 0.125f;
        mx = fmaxf(mx, accS[i][j][r]);
      }
#pragma unroll
      for (int off = 1; off < 16; off <<= 1) mx = fmaxf(mx, __shfl_xor(mx, off));
      float s = 0.f;
#pragma unroll
      for (int j = 0; j < 8; ++j) {
        float e = __expf(accS[i][j][r] - mx);
        accS[i][j][r] = e;
        s += e;
      }
#pragma unroll
      for (int off = 1; off < 16; off <<= 1) s += __shfl_xor(s, off);
      rinv[i][r] = 1.f / s;
      int prow = wave * 32 + i * 16 + quad * 4 + r;
#pragma unroll
      for (int j = 0; j < 8; ++j)
        Ps[prow * 136 + j * 16 + ll] = (_Float16)accS[i][j][r];
    }
  }
  __syncthreads();
#pragma unroll
  for (int it = 0; it < 4; ++it) {
    int e = tid + it * 256;
    int vr = e >> 3, c = (e & 7) * 8;
    half8 v = *(const half8*)&Vp[koff + (long)vr * ks + c];
#pragma unroll
    for (int j = 0; j < 8; ++j) KV[(c + j) * 132 + vr] = v[j];
  }
  __syncthreads();
  floatx4 accO[2][4];
#pragma unroll
  for (int i = 0; i < 2; ++i)
#pragma unroll
    for (int j = 0; j < 4; ++j) accO[i][j] = (floatx4){0.f, 0.f, 0.f, 0.f};
#pragma unroll
  for (int k4 = 0; k4 < 4; ++k4) {
    half8 aP[2];
#pragma unroll
    for (int i = 0; i < 2; ++i)
      aP[i] = *(const half8*)&Ps[(wave * 32 + i * 16 + ll) * 136 + quad * 8 + k4 * 32];
#pragma unroll
    for (int jh = 0; jh < 4; ++jh) {
      int vb = (jh * 16 + ll) * 132 + quad * 8 + k4 * 32;
      half4 v0 = *(const half4*)&KV[vb];
      half4 v1 = *(const half4*)&KV[vb + 4];
      half8 bV = __builtin_shufflevector(v0, v1, 0, 1, 2, 3, 4, 5, 6, 7);
      accO[0][jh] = __builtin_amdgcn_mfma_f32_16x16x32_f16(aP[0], bV, accO[0][jh], 0, 0, 0);
      accO[1][jh] = __builtin_amdgcn_mfma_f32_16x16x32_f16(aP[1], bV, accO[1][jh], 0, 0, 0);
    }
  }
#pragma unroll
  for (int i = 0; i < 2; ++i)
#pragma unroll
    for (int jh = 0; jh < 4; ++jh)
#pragma unroll
      for (int r = 0; r < 4; ++r) {
        int m = wave * 32 + i * 16 + quad * 4 + r;
        Op[obase + (long)m * 512 + jh * 16 + ll] = (_Float16)(accO[i][jh][r] * rinv[i][r]);
      }
}

// ---------------- Residual + LayerNorm (rows of 512, fp32 math). One wave per row.
__global__ __launch_bounds__(256) void ln_h(
    const void* __restrict__ xin, int xf32, const _Float16* __restrict__ add,
    _Float16* __restrict__ out, const float* __restrict__ g,
    const float* __restrict__ bt, long row0, int bmask)
{
  int rl = blockIdx.x * 4 + (threadIdx.x >> 6);
  long row = row0 + rl;
  int lane = threadIdx.x & 63;
  long xr = (row & (long)bmask) * 512 + lane * 8;
  float v[8];
  if (xf32) {
    float4 a0 = *(const float4*)((const float*)xin + xr);
    float4 a1 = *(const float4*)((const float*)xin + xr + 4);
    v[0] = a0.x; v[1] = a0.y; v[2] = a0.z; v[3] = a0.w;
    v[4] = a1.x; v[5] = a1.y; v[6] = a1.z; v[7] = a1.w;
  } else {
    half8 h = *(const half8*)((const _Float16*)xin + xr);
#pragma unroll
    for (int i = 0; i < 8; ++i) v[i] = (float)h[i];
  }
  if (add) {
    half8 a = *(const half8*)&add[(long)rl * 512 + lane * 8];
#pragma unroll
    for (int i = 0; i < 8; ++i) v[i] += (float)a[i];
  }
  float s = 0.f, sq = 0.f;
#pragma unroll
  for (int i = 0; i < 8; ++i) { s += v[i]; sq += v[i] * v[i]; }
#pragma unroll
  for (int off = 1; off < 64; off <<= 1) {
    s += __shfl_xor(s, off);
    sq += __shfl_xor(sq, off);
  }
  float mean = s * (1.f / 512.f);
  float var = sq * (1.f / 512.f) - mean * mean;
  float rst = rsqrtf(var + 1e-6f);
  int c = lane * 8;
  float4 g0 = *(const float4*)&g[c], g1 = *(const float4*)&g[c + 4];
  float4 b0 = *(const float4*)&bt[c], b1 = *(const float4*)&bt[c + 4];
  float gg[8] = {g0.x, g0.y, g0.z, g0.w, g1.x, g1.y, g1.z, g1.w};
  float bb[8] = {b0.x, b0.y, b0.z, b0.w, b1.x, b1.y, b1.z, b1.w};
  half8 o;
#pragma unroll
  for (int i = 0; i < 8; ++i) o[i] = (_Float16)((v[i] - mean) * rst * gg[i] + bb[i]);
  *(half8*)&out[row * 512 + c] = o;
}

// ---------------- batched 512x512 transpose-convert (12 weights in one launch)
__global__ __launch_bounds__(256) void tconv512(
    const float* __restrict__ w0, const float* __restrict__ w1,
    const float* __restrict__ w2, const float* __restrict__ w3,
    const float* __restrict__ w4, const float* __restrict__ w5,
    _Float16* __restrict__ Wh)
{
  __shared__ float T[64][65];
  int z = blockIdx.z;
  int t = z >> 1, l = z & 1;
  const float* src;
  long off;
  switch (t) {
    case 0: src = w0; off = 0; break;
    case 1: src = w1; off = 262144; break;
    case 2: src = w2; off = 524288; break;
    case 3: src = w3; off = 1048576; break;
    case 4: src = w4; off = 1310720; break;
    default: src = w5; off = 1572864; break;
  }
  src += (long)l * 262144;
  _Float16* out = Wh + (long)l * 4194304 + off;
  int tx = threadIdx.x & 63, tg = threadIdx.x >> 6;
  int r0 = blockIdx.y * 64, c0 = blockIdx.x * 64;
#pragma unroll
  for (int i = 0; i < 16; ++i)
    T[tg + 4 * i][tx] = src[(long)(r0 + tg + 4 * i) * 512 + c0 + tx];
  __syncthreads();
#pragma unroll
  for (int i = 0; i < 16; ++i)
    out[(long)(c0 + tg + 4 * i) * 512 + r0 + tx] = (_Float16)T[tx][tg + 4 * i];
}

// ---------------- layered transpose-convert for FFN weights
__global__ __launch_bounds__(256) void tconvL(const float* __restrict__ in,
                                              _Float16* __restrict__ out, int Rr, int Cc,
                                              long ils, long ols)
{
  __shared__ float T[64][65];
  in += (long)blockIdx.z * ils;
  out += (long)blockIdx.z * ols;
  int tx = threadIdx.x & 63, tg = threadIdx.x >> 6;
  int r0 = blockIdx.y * 64, c0 = blockIdx.x * 64;
#pragma unroll
  for (int i = 0; i < 16; ++i)
    T[tg + 4 * i][tx] = in[(long)(r0 + tg + 4 * i) * Cc + c0 + tx];
  __syncthreads();
#pragma unroll
  for (int i = 0; i < 16; ++i)
    out[(long)(c0 + tg + 4 * i) * Rr + r0 + tx] = (_Float16)T[tx][tg + 4 * i];
}

// ---------------- batched wo conversion
__global__ void woconvB(const float* __restrict__ sa_wo, const float* __restrict__ ca_wo,
                        _Float16* __restrict__ Wh)
{
  int z = blockIdx.y;
  int s = z >> 1, l = z & 1;
  const float* wo = (s ? ca_wo : sa_wo) + (long)l * 262144;
  _Float16* out = Wh + (long)l * 4194304 + (s ? 1835008 : 786432);
  int o = blockIdx.x * 256 + threadIdx.x;  // 262144
  int d = o >> 9;
  int nh = o & 511;
  int n = nh >> 6, h = nh & 63;
  out[o] = (_Float16)wo[((long)(n << 9) + d) * 64 + h];
}

// ---------------- pack all biases in one launch
__global__ void packbias(const float* __restrict__ sa_bq, const float* __restrict__ sa_bk,
                         const float* __restrict__ sa_bv, const float* __restrict__ ca_bk,
                         const float* __restrict__ ca_bv, float* __restrict__ Bqkv,
                         float* __restrict__ Bkv)
{
  int i = blockIdx.x * 256 + threadIdx.x;
  if (i >= 5120) return;
  int reg = i >> 9, idx = i & 511;
  int l = reg / 5, r = reg % 5;
  int lo = l * 512;
  switch (r) {
    case 0: Bqkv[l * 1536 + idx] = sa_bq[lo + idx]; break;
    case 1: Bqkv[l * 1536 + 512 + idx] = sa_bk[lo + idx]; break;
    case 2: Bqkv[l * 1536 + 1024 + idx] = sa_bv[lo + idx]; break;
    case 3: Bkv[l * 1024 + idx] = ca_bk[lo + idx]; break;
    default: Bkv[l * 1024 + 512 + idx] = ca_bv[lo + idx]; break;
  }
}

// ---------------- fused fp32->fp16 for c and q
__global__ void f2h2(const float* __restrict__ a, _Float16* __restrict__ oa, long na,
                     const float* __restrict__ bsrc, _Float16* __restrict__ ob, long nb)
{
  long i = blockIdx.x * 256L + threadIdx.x;
  if (i < na) oa[i] = (_Float16)a[i];
  else if (i < na + nb) ob[i - na] = (_Float16)bsrc[i - na];
}

// ---------------- mean over tokens 1..127 -> [ab, 512]
__global__ void pool_h(const _Float16* __restrict__ X, float* __restrict__ P)
{
  int ab = blockIdx.x;
  for (int dd = threadIdx.x; dd < 512; dd += 256) {
    const _Float16* base = X + (long)ab * 65536 + dd;
    float s = 0.f;
    for (int t = 1; t < 128; ++t) s += (float)base[t * 512];
    P[ab * 512 + dd] = s * (1.f / 127.f);
  }
}

__global__ void pool_f(const float* __restrict__ X, float* __restrict__ P)
{
  int ab = blockIdx.x;
  for (int dd = threadIdx.x; dd < 512; dd += 256) {
    const float* base = X + (long)ab * 65536 + dd;
    float s = 0.f;
    for (int t = 1; t < 128; ++t) s += base[t * 512];
    P[ab * 512 + dd] = s * (1.f / 127.f);
  }
}

__global__ void featq_kernel(const float* __restrict__ QP, const float* __restrict__ W,
                             const float* __restrict__ bias, float* __restrict__ QN)
{
  int a = blockIdx.x;
  int f = threadIdx.x;
  float acc = bias[f];
  const float* xr = QP + a * 512;
  for (int d = 0; d < 512; ++d) acc += xr[d] * W[d * 256 + f];
  __shared__ float red[256];
  red[f] = acc * acc;
  __syncthreads();
  for (int s = 128; s > 0; s >>= 1) {
    if (f < s) red[f] += red[f + s];
    __syncthreads();
  }
  float rn = rsqrtf(fmaxf(red[0], 1e-12f));
  QN[a * 256 + f] = acc * rn;
}

__global__ void featc_kernel(const float* __restrict__ CP, const float* __restrict__ W,
                             const float* __restrict__ bias, const float* __restrict__ QN,
                             float* __restrict__ out)
{
  int ab = blockIdx.x;
  int f = threadIdx.x;
  float acc = bias[f];
  const float* xr = CP + ab * 512;
  for (int d = 0; d < 512; ++d) acc += xr[d] * W[d * 256 + f];
  __shared__ float red[256];
  red[f] = acc * acc;
  __syncthreads();
  for (int s = 128; s > 0; s >>= 1) {
    if (f < s) red[f] += red[f + s];
    __syncthreads();
  }
  float rn = rsqrtf(fmaxf(red[0], 1e-12f));
  float v = acc * rn * QN[(ab >> 5) * 256 + f];
  __syncthreads();
  red[f] = v;
  __syncthreads();
  for (int s = 128; s > 0; s >>= 1) {
    if (f < s) red[f] += red[f + s];
    __syncthreads();
  }
  if (f == 0) out[ab] = red[0];
}

extern "C" void kernel_launch(void* const* d_in, const int* in_sizes, int n_in,
                              void* d_out, int out_size, void* d_ws, size_t ws_size,
                              hipStream_t stream)
{
  (void)in_sizes; (void)n_in; (void)out_size;
  const float* c_in  = (const float*)d_in[0];
  const float* q_in  = (const float*)d_in[1];
  const float* sa_wq = (const float*)d_in[2];
  const float* sa_bq = (const float*)d_in[3];
  const float* sa_wk = (const float*)d_in[4];
  const float* sa_bk = (const float*)d_in[5];
  const float* sa_wv = (const float*)d_in[6];
  const float* sa_bv = (const float*)d_in[7];
  const float* sa_wo = (const float*)d_in[8];
  const float* sa_bo = (const float*)d_in[9];
  const float* ca_wq = (const float*)d_in[10];
  const float* ca_bq = (const float*)d_in[11];
  const float* ca_wk = (const float*)d_in[12];
  const float* ca_bk = (const float*)d_in[13];
  const float* ca_wv = (const float*)d_in[14];
  const float* ca_bv = (const float*)d_in[15];
  const float* ca_wo = (const float*)d_in[16];
  const float* ca_bo = (const float*)d_in[17];
  const float* ln1_g = (const float*)d_in[18];
  const float* ln1_b = (const float*)d_in[19];
  const float* ln2_g = (const float*)d_in[20];
  const float* ln2_b = (const float*)d_in[21];
  const float* ln3_g = (const float*)d_in[22];
  const float* ln3_b = (const float*)d_in[23];
  const float* ffn_w1 = (const float*)d_in[24];
  const float* ffn_b1 = (const float*)d_in[25];
  const float* ffn_w2 = (const float*)d_in[26];
  const float* ffn_b2 = (const float*)d_in[27];
  const float* lnf_g  = (const float*)d_in[28];
  const float* lnf_b  = (const float*)d_in[29];
  const float* feat_wq = (const float*)d_in[30];
  const float* feat_bq = (const float*)d_in[31];
  const float* feat_wc = (const float*)d_in[32];
  const float* feat_bc = (const float*)d_in[33];

  // ---- workspace layout
  char* p = (char*)d_ws;
  _Float16* Xh  = (_Float16*)p;  p += 33554432;  // 32768 x 512 fp16 residual stream
  _Float16* Xsh = (_Float16*)p;  p += 4194304;   //  4096 x 512 fp16 (layer-0 x)
  _Float16* Wh  = (_Float16*)p;  p += 16777216;  // fp16 weight arena (2 layers)
  _Float16* qh  = (_Float16*)p;  p += 1048576;   //  1024 x 512 fp16
  _Float16* KV0 = (_Float16*)p;  p += 2097152;   //  1024 x 1024 fp16 (K|V)
  float*    Bqkv = (float*)p;    p += 12288;
  float*    Bkv  = (float*)p;    p += 8192;
  float*    CP  = (float*)p;     p += 524288;
  float*    QP  = (float*)p;     p += 16384;
  float*    QN  = (float*)p;     p += 8192;
  const size_t fixed_b = (size_t)(p - (char*)d_ws);
  long R = 4096;
  if (ws_size >= fixed_b + 5120UL * 32768) R = 32768;
  else if (ws_size >= fixed_b + 5120UL * 16384) R = 16384;
  else if (ws_size >= fixed_b + 5120UL * 8192) R = 8192;
  _Float16* QKVc = (_Float16*)p; p += R * 3072;  // [R][1536]
  _Float16* Oc   = (_Float16*)p; p += R * 1024;  // [R][512]
  _Float16* Ac   = (_Float16*)p;                 // [R][512]
  _Float16* Hb = QKVc;            // FFN hidden [R/2][2048] aliases QKVc
  const long Rh = R / 2;

  // ---- prep (6 launches)
  f2h2<<<10240, 256, 0, stream>>>(c_in, Xsh, 2097152, q_in, qh, 524288);
  tconv512<<<dim3(8, 8, 12), 256, 0, stream>>>(sa_wq, sa_wk, sa_wv, ca_wq, ca_wk, ca_wv, Wh);
  woconvB<<<dim3(1024, 4), 256, 0, stream>>>(sa_wo, ca_wo, Wh);
  tconvL<<<dim3(32, 8, 2), 256, 0, stream>>>(ffn_w1, Wh + 2097152, 512, 2048, 1048576, 4194304);
  tconvL<<<dim3(8, 32, 2), 256, 0, stream>>>(ffn_w2, Wh + 3145728, 2048, 512, 1048576, 4194304);
  packbias<<<20, 256, 0, stream>>>(sa_bq, sa_bk, sa_bv, ca_bk, ca_bv, Bqkv, Bkv);

  // =================== layer 0 (x rows = 4096) ===================
  {
    _Float16* Wl = Wh;
    gemm_h<<<dim3(12, 32), 256, 0, stream>>>(Xsh, Wl + 0, Bqkv, QKVc, 4096, 1536, 512, 1536, 0);
    attn_h<<<256, 256, 0, stream>>>(QKVc, 1536, QKVc + 512, QKVc + 1024, 1536, Oc, 0, 0, 0);
    gemm_h<<<dim3(4, 32), 256, 0, stream>>>(Oc, Wl + 786432, sa_bo, Ac, 4096, 512, 512, 512, 0);
    ln_h<<<1024, 256, 0, stream>>>(c_in, 1, Ac, Xsh, ln1_g, ln1_b, 0, 0x7FFFFFFF);
    gemm_h<<<dim3(4, 32), 256, 0, stream>>>(Xsh, Wl + 1048576, ca_bq, QKVc, 4096, 512, 512, 1536, 0);
    gemm_h<<<dim3(8, 8), 256, 0, stream>>>(qh, Wl + 1310720, Bkv, KV0, 1024, 1024, 512, 1024, 0);
    for (long c = 0; c < 32768; c += R) {
      attn_h<<<(R / 128) * 8, 256, 0, stream>>>(QKVc, 1536, KV0, KV0 + 512, 1024, Oc,
                                                1, 1, (int)(c / 128));
      gemm_2<<<dim3(4, R / 256), 256, 0, stream>>>(Oc, Wl + 1835008, ca_bo, Ac,
                                                   (int)R, 512, 512, 512, 0);
      ln_h<<<R / 4, 256, 0, stream>>>(Xsh, 0, Ac, Xh, ln2_g, ln2_b, c, 4095);
      for (long s = 0; s < R; s += Rh) {
        gemm_2<<<dim3(16, Rh / 256), 256, 0, stream>>>(Xh + (c + s) * 512, Wl + 2097152,
                                                       ffn_b1, Hb, (int)Rh, 2048, 512, 2048, 1);
        gemm_2<<<dim3(4, Rh / 256), 256, 0, stream>>>(Hb, Wl + 3145728, ffn_b2,
                                                      Ac + s * 512, (int)Rh, 512, 2048, 512, 0);
      }
      ln_h<<<R / 4, 256, 0, stream>>>(Xh, 0, Ac, Xh, ln3_g, ln3_b, c, 0x7FFFFFFF);
    }
  }
  // =================== layer 1 (x rows = 32768) ===================
  {
    _Float16* Wl = Wh + 4194304;
    gemm_h<<<dim3(8, 8), 256, 0, stream>>>(qh, Wl + 1310720, Bkv + 1024, KV0, 1024, 1024, 512, 1024, 0);
    for (long c = 0; c < 32768; c += R) {
      _Float16* Xhc = Xh + c * 512;
      gemm_2<<<dim3(12, R / 256), 256, 0, stream>>>(Xhc, Wl + 0, Bqkv + 1536, QKVc,
                                                    (int)R, 1536, 512, 1536, 0);
      attn_h<<<(R / 128) * 8, 256, 0, stream>>>(QKVc, 1536, QKVc + 512, QKVc + 1024, 1536,
                                                Oc, 0, 0, 0);
      gemm_2<<<dim3(4, R / 256), 256, 0, stream>>>(Oc, Wl + 786432, sa_bo + 512, Ac,
                                                   (int)R, 512, 512, 512, 0);
      ln_h<<<R / 4, 256, 0, stream>>>(Xh, 0, Ac, Xh, ln1_g + 512, ln1_b + 512, c, 0x7FFFFFFF);
      gemm_2<<<dim3(4, R / 256), 256, 0, stream>>>(Xhc, Wl + 1048576, ca_bq + 512, QKVc,
                                                   (int)R, 512, 512, 1536, 0);
      attn_h<<<(R / 128) * 8, 256, 0, stream>>>(QKVc, 1536, KV0, KV0 + 512, 1024, Oc,
                                                1, 0, (int)(c / 128));
      gemm_2<<<dim3(4, R / 256), 256, 0, stream>>>(Oc, Wl + 1835008, ca_bo + 512, Ac,
                                                   (int)R, 512, 512, 512, 0);
      ln_h<<<R / 4, 256, 0, stream>>>(Xh, 0, Ac, Xh, ln2_g + 512, ln2_b + 512, c, 0x7FFFFFFF);
      for (long s = 0; s < R; s += Rh) {
        gemm_2<<<dim3(16, Rh / 256), 256, 0, stream>>>(Xh + (c + s) * 512, Wl + 2097152,
                                                       ffn_b1 + 2048, Hb, (int)Rh, 2048, 512, 2048, 1);
        gemm_2<<<dim3(4, Rh / 256), 256, 0, stream>>>(Hb, Wl + 3145728, ffn_b2 + 512,
                                                      Ac + s * 512, (int)Rh, 512, 2048, 512, 0);
      }
      ln_h<<<R / 4, 256, 0, stream>>>(Xh, 0, Ac, Xh, ln3_g + 512, ln3_b + 512, c, 0x7FFFFFFF);
    }
  }
  // =================== final LN + pooling + features + cosine ===================
  ln_h<<<8192, 256, 0, stream>>>(Xh, 0, nullptr, Xh, lnf_g, lnf_b, 0, 0x7FFFFFFF);
  pool_h<<<256, 256, 0, stream>>>(Xh, CP);
  pool_f<<<8, 256, 0, stream>>>(q_in, QP);
  featq_kernel<<<8, 256, 0, stream>>>(QP, feat_wq, feat_bq, QN);
  featc_kernel<<<256, 256, 0, stream>>>(CP, feat_wc, feat_bc, QN, (float*)d_out);
}

// Round 10
// 1056.078 us; speedup vs baseline: 1.4389x; 1.1103x over previous
//
#include <hip/hip_runtime.h>

using half4  = __attribute__((ext_vector_type(4))) _Float16;
using half8  = __attribute__((ext_vector_type(8))) _Float16;
using floatx4 = __attribute__((ext_vector_type(4))) float;

__device__ __forceinline__ void gl_lds16(const _Float16* g, _Float16* l)
{
  __builtin_amdgcn_global_load_lds(
      (const __attribute__((address_space(1))) void*)g,
      (__attribute__((address_space(3))) void*)l, 16, 0, 0);
}

// ---------------- MFMA fp16 GEMM (128x128 tile, BK=32, seg-XOR swizzled)
__global__ __launch_bounds__(256) void gemm_h(
    const _Float16* __restrict__ A, const _Float16* __restrict__ Bt,
    const float* __restrict__ bias, _Float16* __restrict__ C,
    int M, int N, int K, int ldC, int relu)
{
  __shared__ _Float16 As[128 * 32];
  __shared__ _Float16 Bs[128 * 32];
  int tid = threadIdx.x;
  int lane = tid & 63, wave = tid >> 6;
  long bm0 = (long)blockIdx.y * 128;
  int bn0 = blockIdx.x * 128;
  int wm = (wave & 1) * 64, wn = (wave >> 1) * 64;
  int srow = wave * 16 + (lane >> 2);
  int scol = (((lane & 3) ^ ((lane >> 3) & 3)) * 8);
  const _Float16* aA0 = A + (bm0 + srow) * (long)K + scol;
  const _Float16* aA1 = aA0 + 64 * (long)K;
  const _Float16* aB0 = Bt + (bn0 + srow) * (long)K + scol;
  const _Float16* aB1 = aB0 + 64 * (long)K;
  _Float16* lA0 = As + wave * 512;
  _Float16* lA1 = As + 2048 + wave * 512;
  _Float16* lB0 = Bs + wave * 512;
  _Float16* lB1 = Bs + 2048 + wave * 512;
  int mrow = lane & 15, quad = lane >> 4;
  int cofs = (quad ^ ((mrow >> 1) & 3)) * 8;
  floatx4 acc[4][4];
#pragma unroll
  for (int i = 0; i < 4; ++i)
#pragma unroll
    for (int j = 0; j < 4; ++j) acc[i][j] = (floatx4){0.f, 0.f, 0.f, 0.f};

  for (int kt = 0; kt < K; kt += 32) {
    __syncthreads();
    gl_lds16(aA0 + kt, lA0);
    gl_lds16(aA1 + kt, lA1);
    gl_lds16(aB0 + kt, lB0);
    gl_lds16(aB1 + kt, lB1);
    __syncthreads();
    half8 af[4], bf[4];
#pragma unroll
    for (int i = 0; i < 4; ++i)
      af[i] = *(const half8*)&As[(wm + 16 * i + mrow) * 32 + cofs];
#pragma unroll
    for (int j = 0; j < 4; ++j)
      bf[j] = *(const half8*)&Bs[(wn + 16 * j + mrow) * 32 + cofs];
#pragma unroll
    for (int i = 0; i < 4; ++i)
#pragma unroll
      for (int j = 0; j < 4; ++j)
        acc[i][j] = __builtin_amdgcn_mfma_f32_16x16x32_f16(af[i], bf[j], acc[i][j], 0, 0, 0);
  }
#pragma unroll
  for (int j = 0; j < 4; ++j) {
    int n = bn0 + wn + 16 * j + mrow;
    float bj = bias[n];
#pragma unroll
    for (int i = 0; i < 4; ++i) {
#pragma unroll
      for (int r = 0; r < 4; ++r) {
        long m = bm0 + wm + 16 * i + quad * 4 + r;
        float v = acc[i][j][r] + bj;
        if (relu) v = fmaxf(v, 0.f);
        C[m * (long)ldC + n] = (_Float16)v;
      }
    }
  }
}

// ---------------- MFMA fp16 GEMM (256x128 tile, BK=64, XCD-banded block remap)
// Grid is 1-D (MT*NT blocks). XCD x (= L&7) owns M-band [x*MT/8, (x+1)*MT/8),
// iterating N-tiles innermost -> A-tiles stay in that XCD's L2.
// LDS: row stride 64 halfs (128 B); seg s of row r holds global seg s^(r&7)
// -> MFMA b128 reads hit 2 lanes/bank (free). MT % 8 == 0 required.
__global__ __launch_bounds__(256, 2) void gemm_2(
    const _Float16* __restrict__ A, const _Float16* __restrict__ Bt,
    const float* __restrict__ bias, _Float16* __restrict__ C,
    int MT, int NT, int K, int ldC, int relu)
{
  __shared__ _Float16 As[256 * 64];   // 32 KB
  __shared__ _Float16 Bs[128 * 64];   // 16 KB
  int tid = threadIdx.x;
  int lane = tid & 63, wave = tid >> 6;
  int L = blockIdx.x;
  int xcd = L & 7, seq = L >> 3;
  int band = MT >> 3;
  int mt = xcd * band + seq / NT;
  int nt = seq - (seq / NT) * NT;
  long bm0 = (long)mt * 256;
  int bn0 = nt * 128;
  int r8 = lane >> 3, s8 = lane & 7;
  int scol = (s8 ^ r8) * 8;            // swizzled global source seg
  const _Float16* aA = A + (bm0 + wave * 64 + r8) * (long)K + scol;
  const _Float16* aB = Bt + (bn0 + wave * 32 + r8) * (long)K + scol;
  _Float16* lA = As + (wave * 64) * 64;
  _Float16* lB = Bs + (wave * 32) * 64;
  int ll = lane & 15, quad = lane >> 4;
  int lw = ll & 7;                     // row&7 for reader swizzle
  floatx4 acc[4][8];
#pragma unroll
  for (int i = 0; i < 4; ++i)
#pragma unroll
    for (int j = 0; j < 8; ++j) acc[i][j] = (floatx4){0.f, 0.f, 0.f, 0.f};

  for (int kt = 0; kt < K; kt += 64) {
    __syncthreads();
#pragma unroll
    for (int o = 0; o < 8; ++o)
      gl_lds16(aA + (long)(o * 8) * K + kt, lA + o * 512);
#pragma unroll
    for (int o = 0; o < 4; ++o)
      gl_lds16(aB + (long)(o * 8) * K + kt, lB + o * 512);
    __syncthreads();
#pragma unroll
    for (int k2 = 0; k2 < 2; ++k2) {
      int sofs = ((k2 * 4 + quad) ^ lw) * 8;
      half8 af[4], bf[8];
#pragma unroll
      for (int i = 0; i < 4; ++i)
        af[i] = *(const half8*)&As[(wave * 64 + 16 * i + ll) * 64 + sofs];
#pragma unroll
      for (int j = 0; j < 8; ++j)
        bf[j] = *(const half8*)&Bs[(16 * j + ll) * 64 + sofs];
#pragma unroll
      for (int i = 0; i < 4; ++i)
#pragma unroll
        for (int j = 0; j < 8; ++j)
          acc[i][j] = __builtin_amdgcn_mfma_f32_16x16x32_f16(af[i], bf[j], acc[i][j], 0, 0, 0);
    }
  }
#pragma unroll
  for (int j = 0; j < 8; ++j) {
    int n = bn0 + 16 * j + ll;
    float bj = bias[n];
#pragma unroll
    for (int i = 0; i < 4; ++i) {
#pragma unroll
      for (int r = 0; r < 4; ++r) {
        long m = bm0 + wave * 64 + 16 * i + quad * 4 + r;
        float v = acc[i][j][r] + bj;
        if (relu) v = fmaxf(v, 0.f);
        C[m * (long)ldC + n] = (_Float16)v;
      }
    }
  }
}

// ---------------- MFMA fused attention (unchanged)
__global__ __launch_bounds__(256) void attn_h(
    const _Float16* __restrict__ Qp, int qs,
    const _Float16* __restrict__ Kp, const _Float16* __restrict__ Vp, int ks,
    _Float16* __restrict__ Op, int mode_ca, int l0, int rb0)
{
  __shared__ _Float16 KV[128 * 72];
  __shared__ _Float16 Ps[128 * 136];
  int tid = threadIdx.x;
  int lane = tid & 63, wave = tid >> 6;
  int ll = lane & 15, quad = lane >> 4;
  int idx = blockIdx.x;
  int n = idx & 7;
  int rl = idx >> 3;
  long obase = (long)rl * 128 * 512 + n * 64;
  long qoff, koff;
  if (!mode_ca) {
    qoff = (long)rl * 128 * qs + n * 64;
    koff = (long)rl * 128 * ks + n * 64;
  } else {
    int g = rb0 + rl;
    int a = g >> 5;
    int qblk = l0 ? (g & 31) : rl;
    qoff = (long)qblk * 128 * qs + n * 64;
    koff = (long)a * 128 * ks + n * 64;
  }
#pragma unroll
  for (int it = 0; it < 4; ++it) {
    int e = tid + it * 256;
    int r = e >> 3, c = (e & 7) * 8;
    *(half8*)&KV[r * 72 + c] = *(const half8*)&Kp[koff + (long)r * ks + c];
  }
  half8 aQ[2][2];
#pragma unroll
  for (int i = 0; i < 2; ++i)
#pragma unroll
    for (int k2 = 0; k2 < 2; ++k2)
      aQ[i][k2] = *(const half8*)&Qp[qoff + (long)(wave * 32 + i * 16 + ll) * qs
                                     + quad * 8 + k2 * 32];
  __syncthreads();
  floatx4 accS[2][8];
#pragma unroll
  for (int i = 0; i < 2; ++i)
#pragma unroll
    for (int j = 0; j < 8; ++j) accS[i][j] = (floatx4){0.f, 0.f, 0.f, 0.f};
#pragma unroll
  for (int k2 = 0; k2 < 2; ++k2) {
#pragma unroll
    for (int j = 0; j < 8; ++j) {
      half8 bK = *(const half8*)&KV[(j * 16 + ll) * 72 + quad * 8 + k2 * 32];
      accS[0][j] = __builtin_amdgcn_mfma_f32_16x16x32_f16(aQ[0][k2], bK, accS[0][j], 0, 0, 0);
      accS[1][j] = __builtin_amdgcn_mfma_f32_16x16x32_f16(aQ[1][k2], bK, accS[1][j], 0, 0, 0);
    }
  }
  float rinv[2][4];
#pragma unroll
  for (int i = 0; i < 2; ++i) {
#pragma unroll
    for (int r = 0; r < 4; ++r) {
      float mx = -1e30f;
#pragma unroll
      for (int j = 0; j < 8; ++j) {
        accS[i][j][r] *= 0.125f;
        mx = fmaxf(mx, accS[i][j][r]);
      }
#pragma unroll
      for (int off = 1; off < 16; off <<= 1) mx = fmaxf(mx, __shfl_xor(mx, off));
      float s = 0.f;
#pragma unroll
      for (int j = 0; j < 8; ++j) {
        float e = __expf(accS[i][j][r] - mx);
        accS[i][j][r] = e;
        s += e;
      }
#pragma unroll
      for (int off = 1; off < 16; off <<= 1) s += __shfl_xor(s, off);
      rinv[i][r] = 1.f / s;
      int prow = wave * 32 + i * 16 + quad * 4 + r;
#pragma unroll
      for (int j = 0; j < 8; ++j)
        Ps[prow * 136 + j * 16 + ll] = (_Float16)accS[i][j][r];
    }
  }
  __syncthreads();
#pragma unroll
  for (int it = 0; it < 4; ++it) {
    int e = tid + it * 256;
    int vr = e >> 3, c = (e & 7) * 8;
    half8 v = *(const half8*)&Vp[koff + (long)vr * ks + c];
#pragma unroll
    for (int j = 0; j < 8; ++j) KV[(c + j) * 132 + vr] = v[j];
  }
  __syncthreads();
  floatx4 accO[2][4];
#pragma unroll
  for (int i = 0; i < 2; ++i)
#pragma unroll
    for (int j = 0; j < 4; ++j) accO[i][j] = (floatx4){0.f, 0.f, 0.f, 0.f};
#pragma unroll
  for (int k4 = 0; k4 < 4; ++k4) {
    half8 aP[2];
#pragma unroll
    for (int i = 0; i < 2; ++i)
      aP[i] = *(const half8*)&Ps[(wave * 32 + i * 16 + ll) * 136 + quad * 8 + k4 * 32];
#pragma unroll
    for (int jh = 0; jh < 4; ++jh) {
      int vb = (jh * 16 + ll) * 132 + quad * 8 + k4 * 32;
      half4 v0 = *(const half4*)&KV[vb];
      half4 v1 = *(const half4*)&KV[vb + 4];
      half8 bV = __builtin_shufflevector(v0, v1, 0, 1, 2, 3, 4, 5, 6, 7);
      accO[0][jh] = __builtin_amdgcn_mfma_f32_16x16x32_f16(aP[0], bV, accO[0][jh], 0, 0, 0);
      accO[1][jh] = __builtin_amdgcn_mfma_f32_16x16x32_f16(aP[1], bV, accO[1][jh], 0, 0, 0);
    }
  }
#pragma unroll
  for (int i = 0; i < 2; ++i)
#pragma unroll
    for (int jh = 0; jh < 4; ++jh)
#pragma unroll
      for (int r = 0; r < 4; ++r) {
        int m = wave * 32 + i * 16 + quad * 4 + r;
        Op[obase + (long)m * 512 + jh * 16 + ll] = (_Float16)(accO[i][jh][r] * rinv[i][r]);
      }
}

// ---------------- Residual + LayerNorm (rows of 512, fp32 math). One wave per row.
__global__ __launch_bounds__(256) void ln_h(
    const void* __restrict__ xin, int xf32, const _Float16* __restrict__ add,
    _Float16* __restrict__ out, const float* __restrict__ g,
    const float* __restrict__ bt, long row0, int bmask)
{
  int rl = blockIdx.x * 4 + (threadIdx.x >> 6);
  long row = row0 + rl;
  int lane = threadIdx.x & 63;
  long xr = (row & (long)bmask) * 512 + lane * 8;
  float v[8];
  if (xf32) {
    float4 a0 = *(const float4*)((const float*)xin + xr);
    float4 a1 = *(const float4*)((const float*)xin + xr + 4);
    v[0] = a0.x; v[1] = a0.y; v[2] = a0.z; v[3] = a0.w;
    v[4] = a1.x; v[5] = a1.y; v[6] = a1.z; v[7] = a1.w;
  } else {
    half8 h = *(const half8*)((const _Float16*)xin + xr);
#pragma unroll
    for (int i = 0; i < 8; ++i) v[i] = (float)h[i];
  }
  if (add) {
    half8 a = *(const half8*)&add[(long)rl * 512 + lane * 8];
#pragma unroll
    for (int i = 0; i < 8; ++i) v[i] += (float)a[i];
  }
  float s = 0.f, sq = 0.f;
#pragma unroll
  for (int i = 0; i < 8; ++i) { s += v[i]; sq += v[i] * v[i]; }
#pragma unroll
  for (int off = 1; off < 64; off <<= 1) {
    s += __shfl_xor(s, off);
    sq += __shfl_xor(sq, off);
  }
  float mean = s * (1.f / 512.f);
  float var = sq * (1.f / 512.f) - mean * mean;
  float rst = rsqrtf(var + 1e-6f);
  int c = lane * 8;
  float4 g0 = *(const float4*)&g[c], g1 = *(const float4*)&g[c + 4];
  float4 b0 = *(const float4*)&bt[c], b1 = *(const float4*)&bt[c + 4];
  float gg[8] = {g0.x, g0.y, g0.z, g0.w, g1.x, g1.y, g1.z, g1.w};
  float bb[8] = {b0.x, b0.y, b0.z, b0.w, b1.x, b1.y, b1.z, b1.w};
  half8 o;
#pragma unroll
  for (int i = 0; i < 8; ++i) o[i] = (_Float16)((v[i] - mean) * rst * gg[i] + bb[i]);
  *(half8*)&out[row * 512 + c] = o;
}

// ---------------- batched 512x512 transpose-convert (12 weights in one launch)
__global__ __launch_bounds__(256) void tconv512(
    const float* __restrict__ w0, const float* __restrict__ w1,
    const float* __restrict__ w2, const float* __restrict__ w3,
    const float* __restrict__ w4, const float* __restrict__ w5,
    _Float16* __restrict__ Wh)
{
  __shared__ float T[64][65];
  int z = blockIdx.z;
  int t = z >> 1, l = z & 1;
  const float* src;
  long off;
  switch (t) {
    case 0: src = w0; off = 0; break;
    case 1: src = w1; off = 262144; break;
    case 2: src = w2; off = 524288; break;
    case 3: src = w3; off = 1048576; break;
    case 4: src = w4; off = 1310720; break;
    default: src = w5; off = 1572864; break;
  }
  src += (long)l * 262144;
  _Float16* out = Wh + (long)l * 4194304 + off;
  int tx = threadIdx.x & 63, tg = threadIdx.x >> 6;
  int r0 = blockIdx.y * 64, c0 = blockIdx.x * 64;
#pragma unroll
  for (int i = 0; i < 16; ++i)
    T[tg + 4 * i][tx] = src[(long)(r0 + tg + 4 * i) * 512 + c0 + tx];
  __syncthreads();
#pragma unroll
  for (int i = 0; i < 16; ++i)
    out[(long)(c0 + tg + 4 * i) * 512 + r0 + tx] = (_Float16)T[tx][tg + 4 * i];
}

// ---------------- layered transpose-convert for FFN weights
__global__ __launch_bounds__(256) void tconvL(const float* __restrict__ in,
                                              _Float16* __restrict__ out, int Rr, int Cc,
                                              long ils, long ols)
{
  __shared__ float T[64][65];
  in += (long)blockIdx.z * ils;
  out += (long)blockIdx.z * ols;
  int tx = threadIdx.x & 63, tg = threadIdx.x >> 6;
  int r0 = blockIdx.y * 64, c0 = blockIdx.x * 64;
#pragma unroll
  for (int i = 0; i < 16; ++i)
    T[tg + 4 * i][tx] = in[(long)(r0 + tg + 4 * i) * Cc + c0 + tx];
  __syncthreads();
#pragma unroll
  for (int i = 0; i < 16; ++i)
    out[(long)(c0 + tg + 4 * i) * Rr + r0 + tx] = (_Float16)T[tx][tg + 4 * i];
}

// ---------------- batched wo conversion
__global__ void woconvB(const float* __restrict__ sa_wo, const float* __restrict__ ca_wo,
                        _Float16* __restrict__ Wh)
{
  int z = blockIdx.y;
  int s = z >> 1, l = z & 1;
  const float* wo = (s ? ca_wo : sa_wo) + (long)l * 262144;
  _Float16* out = Wh + (long)l * 4194304 + (s ? 1835008 : 786432);
  int o = blockIdx.x * 256 + threadIdx.x;  // 262144
  int d = o >> 9;
  int nh = o & 511;
  int n = nh >> 6, h = nh & 63;
  out[o] = (_Float16)wo[((long)(n << 9) + d) * 64 + h];
}

// ---------------- pack all biases in one launch
__global__ void packbias(const float* __restrict__ sa_bq, const float* __restrict__ sa_bk,
                         const float* __restrict__ sa_bv, const float* __restrict__ ca_bk,
                         const float* __restrict__ ca_bv, float* __restrict__ Bqkv,
                         float* __restrict__ Bkv)
{
  int i = blockIdx.x * 256 + threadIdx.x;
  if (i >= 5120) return;
  int reg = i >> 9, idx = i & 511;
  int l = reg / 5, r = reg % 5;
  int lo = l * 512;
  switch (r) {
    case 0: Bqkv[l * 1536 + idx] = sa_bq[lo + idx]; break;
    case 1: Bqkv[l * 1536 + 512 + idx] = sa_bk[lo + idx]; break;
    case 2: Bqkv[l * 1536 + 1024 + idx] = sa_bv[lo + idx]; break;
    case 3: Bkv[l * 1024 + idx] = ca_bk[lo + idx]; break;
    default: Bkv[l * 1024 + 512 + idx] = ca_bv[lo + idx]; break;
  }
}

// ---------------- fused fp32->fp16 for c and q
__global__ void f2h2(const float* __restrict__ a, _Float16* __restrict__ oa, long na,
                     const float* __restrict__ bsrc, _Float16* __restrict__ ob, long nb)
{
  long i = blockIdx.x * 256L + threadIdx.x;
  if (i < na) oa[i] = (_Float16)a[i];
  else if (i < na + nb) ob[i - na] = (_Float16)bsrc[i - na];
}

// ---------------- mean over tokens 1..127 -> [ab, 512]
__global__ void pool_h(const _Float16* __restrict__ X, float* __restrict__ P)
{
  int ab = blockIdx.x;
  for (int dd = threadIdx.x; dd < 512; dd += 256) {
    const _Float16* base = X + (long)ab * 65536 + dd;
    float s = 0.f;
    for (int t = 1; t < 128; ++t) s += (float)base[t * 512];
    P[ab * 512 + dd] = s * (1.f / 127.f);
  }
}

__global__ void pool_f(const float* __restrict__ X, float* __restrict__ P)
{
  int ab = blockIdx.x;
  for (int dd = threadIdx.x; dd < 512; dd += 256) {
    const float* base = X + (long)ab * 65536 + dd;
    float s = 0.f;
    for (int t = 1; t < 128; ++t) s += base[t * 512];
    P[ab * 512 + dd] = s * (1.f / 127.f);
  }
}

__global__ void featq_kernel(const float* __restrict__ QP, const float* __restrict__ W,
                             const float* __restrict__ bias, float* __restrict__ QN)
{
  int a = blockIdx.x;
  int f = threadIdx.x;
  float acc = bias[f];
  const float* xr = QP + a * 512;
  for (int d = 0; d < 512; ++d) acc += xr[d] * W[d * 256 + f];
  __shared__ float red[256];
  red[f] = acc * acc;
  __syncthreads();
  for (int s = 128; s > 0; s >>= 1) {
    if (f < s) red[f] += red[f + s];
    __syncthreads();
  }
  float rn = rsqrtf(fmaxf(red[0], 1e-12f));
  QN[a * 256 + f] = acc * rn;
}

__global__ void featc_kernel(const float* __restrict__ CP, const float* __restrict__ W,
                             const float* __restrict__ bias, const float* __restrict__ QN,
                             float* __restrict__ out)
{
  int ab = blockIdx.x;
  int f = threadIdx.x;
  float acc = bias[f];
  const float* xr = CP + ab * 512;
  for (int d = 0; d < 512; ++d) acc += xr[d] * W[d * 256 + f];
  __shared__ float red[256];
  red[f] = acc * acc;
  __syncthreads();
  for (int s = 128; s > 0; s >>= 1) {
    if (f < s) red[f] += red[f + s];
    __syncthreads();
  }
  float rn = rsqrtf(fmaxf(red[0], 1e-12f));
  float v = acc * rn * QN[(ab >> 5) * 256 + f];
  __syncthreads();
  red[f] = v;
  __syncthreads();
  for (int s = 128; s > 0; s >>= 1) {
    if (f < s) red[f] += red[f + s];
    __syncthreads();
  }
  if (f == 0) out[ab] = red[0];
}

extern "C" void kernel_launch(void* const* d_in, const int* in_sizes, int n_in,
                              void* d_out, int out_size, void* d_ws, size_t ws_size,
                              hipStream_t stream)
{
  (void)in_sizes; (void)n_in; (void)out_size;
  const float* c_in  = (const float*)d_in[0];
  const float* q_in  = (const float*)d_in[1];
  const float* sa_wq = (const float*)d_in[2];
  const float* sa_bq = (const float*)d_in[3];
  const float* sa_wk = (const float*)d_in[4];
  const float* sa_bk = (const float*)d_in[5];
  const float* sa_wv = (const float*)d_in[6];
  const float* sa_bv = (const float*)d_in[7];
  const float* sa_wo = (const float*)d_in[8];
  const float* sa_bo = (const float*)d_in[9];
  const float* ca_wq = (const float*)d_in[10];
  const float* ca_bq = (const float*)d_in[11];
  const float* ca_wk = (const float*)d_in[12];
  const float* ca_bk = (const float*)d_in[13];
  const float* ca_wv = (const float*)d_in[14];
  const float* ca_bv = (const float*)d_in[15];
  const float* ca_wo = (const float*)d_in[16];
  const float* ca_bo = (const float*)d_in[17];
  const float* ln1_g = (const float*)d_in[18];
  const float* ln1_b = (const float*)d_in[19];
  const float* ln2_g = (const float*)d_in[20];
  const float* ln2_b = (const float*)d_in[21];
  const float* ln3_g = (const float*)d_in[22];
  const float* ln3_b = (const float*)d_in[23];
  const float* ffn_w1 = (const float*)d_in[24];
  const float* ffn_b1 = (const float*)d_in[25];
  const float* ffn_w2 = (const float*)d_in[26];
  const float* ffn_b2 = (const float*)d_in[27];
  const float* lnf_g  = (const float*)d_in[28];
  const float* lnf_b  = (const float*)d_in[29];
  const float* feat_wq = (const float*)d_in[30];
  const float* feat_bq = (const float*)d_in[31];
  const float* feat_wc = (const float*)d_in[32];
  const float* feat_bc = (const float*)d_in[33];

  // ---- workspace layout
  char* p = (char*)d_ws;
  _Float16* Xh  = (_Float16*)p;  p += 33554432;  // 32768 x 512 fp16 residual stream
  _Float16* Xsh = (_Float16*)p;  p += 4194304;   //  4096 x 512 fp16 (layer-0 x)
  _Float16* Wh  = (_Float16*)p;  p += 16777216;  // fp16 weight arena (2 layers)
  _Float16* qh  = (_Float16*)p;  p += 1048576;   //  1024 x 512 fp16
  _Float16* KV0 = (_Float16*)p;  p += 2097152;   //  1024 x 1024 fp16 (K|V)
  float*    Bqkv = (float*)p;    p += 12288;
  float*    Bkv  = (float*)p;    p += 8192;
  float*    CP  = (float*)p;     p += 524288;
  float*    QP  = (float*)p;     p += 16384;
  float*    QN  = (float*)p;     p += 8192;
  const size_t fixed_b = (size_t)(p - (char*)d_ws);
  long R = 4096;
  if (ws_size >= fixed_b + 5120UL * 32768) R = 32768;
  else if (ws_size >= fixed_b + 5120UL * 16384) R = 16384;
  else if (ws_size >= fixed_b + 5120UL * 8192) R = 8192;
  _Float16* QKVc = (_Float16*)p; p += R * 3072;  // [R][1536]
  _Float16* Oc   = (_Float16*)p; p += R * 1024;  // [R][512]
  _Float16* Ac   = (_Float16*)p;                 // [R][512]
  _Float16* Hb = QKVc;            // FFN hidden [R/2][2048] aliases QKVc
  const long Rh = R / 2;
  const int MTR = (int)(R / 256), MTH = (int)(Rh / 256);

  // ---- prep (6 launches)
  f2h2<<<10240, 256, 0, stream>>>(c_in, Xsh, 2097152, q_in, qh, 524288);
  tconv512<<<dim3(8, 8, 12), 256, 0, stream>>>(sa_wq, sa_wk, sa_wv, ca_wq, ca_wk, ca_wv, Wh);
  woconvB<<<dim3(1024, 4), 256, 0, stream>>>(sa_wo, ca_wo, Wh);
  tconvL<<<dim3(32, 8, 2), 256, 0, stream>>>(ffn_w1, Wh + 2097152, 512, 2048, 1048576, 4194304);
  tconvL<<<dim3(8, 32, 2), 256, 0, stream>>>(ffn_w2, Wh + 3145728, 2048, 512, 1048576, 4194304);
  packbias<<<20, 256, 0, stream>>>(sa_bq, sa_bk, sa_bv, ca_bk, ca_bv, Bqkv, Bkv);

  // =================== layer 0 (x rows = 4096) ===================
  {
    _Float16* Wl = Wh;
    gemm_h<<<dim3(12, 32), 256, 0, stream>>>(Xsh, Wl + 0, Bqkv, QKVc, 4096, 1536, 512, 1536, 0);
    attn_h<<<256, 256, 0, stream>>>(QKVc, 1536, QKVc + 512, QKVc + 1024, 1536, Oc, 0, 0, 0);
    gemm_h<<<dim3(4, 32), 256, 0, stream>>>(Oc, Wl + 786432, sa_bo, Ac, 4096, 512, 512, 512, 0);
    ln_h<<<1024, 256, 0, stream>>>(c_in, 1, Ac, Xsh, ln1_g, ln1_b, 0, 0x7FFFFFFF);
    gemm_h<<<dim3(4, 32), 256, 0, stream>>>(Xsh, Wl + 1048576, ca_bq, QKVc, 4096, 512, 512, 1536, 0);
    gemm_h<<<dim3(8, 8), 256, 0, stream>>>(qh, Wl + 1310720, Bkv, KV0, 1024, 1024, 512, 1024, 0);
    for (long c = 0; c < 32768; c += R) {
      attn_h<<<(R / 128) * 8, 256, 0, stream>>>(QKVc, 1536, KV0, KV0 + 512, 1024, Oc,
                                                1, 1, (int)(c / 128));
      gemm_2<<<MTR * 4, 256, 0, stream>>>(Oc, Wl + 1835008, ca_bo, Ac, MTR, 4, 512, 512, 0);
      ln_h<<<R / 4, 256, 0, stream>>>(Xsh, 0, Ac, Xh, ln2_g, ln2_b, c, 4095);
      for (long s = 0; s < R; s += Rh) {
        gemm_2<<<MTH * 16, 256, 0, stream>>>(Xh + (c + s) * 512, Wl + 2097152,
                                             ffn_b1, Hb, MTH, 16, 512, 2048, 1);
        gemm_2<<<MTH * 4, 256, 0, stream>>>(Hb, Wl + 3145728, ffn_b2,
                                            Ac + s * 512, MTH, 4, 2048, 512, 0);
      }
      ln_h<<<R / 4, 256, 0, stream>>>(Xh, 0, Ac, Xh, ln3_g, ln3_b, c, 0x7FFFFFFF);
    }
  }
  // =================== layer 1 (x rows = 32768) ===================
  {
    _Float16* Wl = Wh + 4194304;
    gemm_h<<<dim3(8, 8), 256, 0, stream>>>(qh, Wl + 1310720, Bkv + 1024, KV0, 1024, 1024, 512, 1024, 0);
    for (long c = 0; c < 32768; c += R) {
      _Float16* Xhc = Xh + c * 512;
      gemm_2<<<MTR * 12, 256, 0, stream>>>(Xhc, Wl + 0, Bqkv + 1536, QKVc, MTR, 12, 512, 1536, 0);
      attn_h<<<(R / 128) * 8, 256, 0, stream>>>(QKVc, 1536, QKVc + 512, QKVc + 1024, 1536,
                                                Oc, 0, 0, 0);
      gemm_2<<<MTR * 4, 256, 0, stream>>>(Oc, Wl + 786432, sa_bo + 512, Ac, MTR, 4, 512, 512, 0);
      ln_h<<<R / 4, 256, 0, stream>>>(Xh, 0, Ac, Xh, ln1_g + 512, ln1_b + 512, c, 0x7FFFFFFF);
      gemm_2<<<MTR * 4, 256, 0, stream>>>(Xhc, Wl + 1048576, ca_bq + 512, QKVc, MTR, 4, 512, 1536, 0);
      attn_h<<<(R / 128) * 8, 256, 0, stream>>>(QKVc, 1536, KV0, KV0 + 512, 1024, Oc,
                                                1, 0, (int)(c / 128));
      gemm_2<<<MTR * 4, 256, 0, stream>>>(Oc, Wl + 1835008, ca_bo + 512, Ac, MTR, 4, 512, 512, 0);
      ln_h<<<R / 4, 256, 0, stream>>>(Xh, 0, Ac, Xh, ln2_g + 512, ln2_b + 512, c, 0x7FFFFFFF);
      for (long s = 0; s < R; s += Rh) {
        gemm_2<<<MTH * 16, 256, 0, stream>>>(Xh + (c + s) * 512, Wl + 2097152,
                                             ffn_b1 + 2048, Hb, MTH, 16, 512, 2048, 1);
        gemm_2<<<MTH * 4, 256, 0, stream>>>(Hb, Wl + 3145728, ffn_b2 + 512,
                                            Ac + s * 512, MTH, 4, 2048, 512, 0);
      }
      ln_h<<<R / 4, 256, 0, stream>>>(Xh, 0, Ac, Xh, ln3_g + 512, ln3_b + 512, c, 0x7FFFFFFF);
    }
  }
  // =================== final LN + pooling + features + cosine ===================
  ln_h<<<8192, 256, 0, stream>>>(Xh, 0, nullptr, Xh, lnf_g, lnf_b, 0, 0x7FFFFFFF);
  pool_h<<<256, 256, 0, stream>>>(Xh, CP);
  pool_f<<<8, 256, 0, stream>>>(q_in, QP);
  featq_kernel<<<8, 256, 0, stream>>>(QP, feat_wq, feat_bq, QN);
  featc_kernel<<<256, 256, 0, stream>>>(CP, feat_wc, feat_bc, QN, (float*)d_out);
}

// Round 11
// 894.028 us; speedup vs baseline: 1.6997x; 1.1813x over previous
//
#include <hip/hip_runtime.h>

using half4  = __attribute__((ext_vector_type(4))) _Float16;
using half8  = __attribute__((ext_vector_type(8))) _Float16;
using floatx4 = __attribute__((ext_vector_type(4))) float;

__device__ __forceinline__ void gl_lds16(const _Float16* g, _Float16* l)
{
  __builtin_amdgcn_global_load_lds(
      (const __attribute__((address_space(1))) void*)g,
      (__attribute__((address_space(3))) void*)l, 16, 0, 0);
}

// ---------------- MFMA fp16 GEMM (128x128 tile, BK=32, seg-XOR swizzled)
__global__ __launch_bounds__(256) void gemm_h(
    const _Float16* __restrict__ A, const _Float16* __restrict__ Bt,
    const float* __restrict__ bias, _Float16* __restrict__ C,
    int M, int N, int K, int ldC, int relu)
{
  __shared__ _Float16 As[128 * 32];
  __shared__ _Float16 Bs[128 * 32];
  int tid = threadIdx.x;
  int lane = tid & 63, wave = tid >> 6;
  long bm0 = (long)blockIdx.y * 128;
  int bn0 = blockIdx.x * 128;
  int wm = (wave & 1) * 64, wn = (wave >> 1) * 64;
  int srow = wave * 16 + (lane >> 2);
  int scol = (((lane & 3) ^ ((lane >> 3) & 3)) * 8);
  const _Float16* aA0 = A + (bm0 + srow) * (long)K + scol;
  const _Float16* aA1 = aA0 + 64 * (long)K;
  const _Float16* aB0 = Bt + (bn0 + srow) * (long)K + scol;
  const _Float16* aB1 = aB0 + 64 * (long)K;
  _Float16* lA0 = As + wave * 512;
  _Float16* lA1 = As + 2048 + wave * 512;
  _Float16* lB0 = Bs + wave * 512;
  _Float16* lB1 = Bs + 2048 + wave * 512;
  int mrow = lane & 15, quad = lane >> 4;
  int cofs = (quad ^ ((mrow >> 1) & 3)) * 8;
  floatx4 acc[4][4];
#pragma unroll
  for (int i = 0; i < 4; ++i)
#pragma unroll
    for (int j = 0; j < 4; ++j) acc[i][j] = (floatx4){0.f, 0.f, 0.f, 0.f};

  for (int kt = 0; kt < K; kt += 32) {
    __syncthreads();
    gl_lds16(aA0 + kt, lA0);
    gl_lds16(aA1 + kt, lA1);
    gl_lds16(aB0 + kt, lB0);
    gl_lds16(aB1 + kt, lB1);
    __syncthreads();
    half8 af[4], bf[4];
#pragma unroll
    for (int i = 0; i < 4; ++i)
      af[i] = *(const half8*)&As[(wm + 16 * i + mrow) * 32 + cofs];
#pragma unroll
    for (int j = 0; j < 4; ++j)
      bf[j] = *(const half8*)&Bs[(wn + 16 * j + mrow) * 32 + cofs];
#pragma unroll
    for (int i = 0; i < 4; ++i)
#pragma unroll
      for (int j = 0; j < 4; ++j)
        acc[i][j] = __builtin_amdgcn_mfma_f32_16x16x32_f16(af[i], bf[j], acc[i][j], 0, 0, 0);
  }
#pragma unroll
  for (int j = 0; j < 4; ++j) {
    int n = bn0 + wn + 16 * j + mrow;
    float bj = bias[n];
#pragma unroll
    for (int i = 0; i < 4; ++i) {
#pragma unroll
      for (int r = 0; r < 4; ++r) {
        long m = bm0 + wm + 16 * i + quad * 4 + r;
        float v = acc[i][j][r] + bj;
        if (relu) v = fmaxf(v, 0.f);
        C[m * (long)ldC + n] = (_Float16)v;
      }
    }
  }
}

// ---------------- MFMA fp16 GEMM (256x128 tile, BK=64, XCD-banded block remap)
__global__ __launch_bounds__(256, 2) void gemm_2(
    const _Float16* __restrict__ A, const _Float16* __restrict__ Bt,
    const float* __restrict__ bias, _Float16* __restrict__ C,
    int MT, int NT, int K, int ldC, int relu)
{
  __shared__ _Float16 As[256 * 64];   // 32 KB
  __shared__ _Float16 Bs[128 * 64];   // 16 KB
  int tid = threadIdx.x;
  int lane = tid & 63, wave = tid >> 6;
  int L = blockIdx.x;
  int xcd = L & 7, seq = L >> 3;
  int band = MT >> 3;
  int mt = xcd * band + seq / NT;
  int nt = seq - (seq / NT) * NT;
  long bm0 = (long)mt * 256;
  int bn0 = nt * 128;
  int r8 = lane >> 3, s8 = lane & 7;
  int scol = (s8 ^ r8) * 8;            // swizzled global source seg
  const _Float16* aA = A + (bm0 + wave * 64 + r8) * (long)K + scol;
  const _Float16* aB = Bt + (bn0 + wave * 32 + r8) * (long)K + scol;
  _Float16* lA = As + (wave * 64) * 64;
  _Float16* lB = Bs + (wave * 32) * 64;
  int ll = lane & 15, quad = lane >> 4;
  int lw = ll & 7;
  floatx4 acc[4][8];
#pragma unroll
  for (int i = 0; i < 4; ++i)
#pragma unroll
    for (int j = 0; j < 8; ++j) acc[i][j] = (floatx4){0.f, 0.f, 0.f, 0.f};

  for (int kt = 0; kt < K; kt += 64) {
    __syncthreads();
#pragma unroll
    for (int o = 0; o < 8; ++o)
      gl_lds16(aA + (long)(o * 8) * K + kt, lA + o * 512);
#pragma unroll
    for (int o = 0; o < 4; ++o)
      gl_lds16(aB + (long)(o * 8) * K + kt, lB + o * 512);
    __syncthreads();
#pragma unroll
    for (int k2 = 0; k2 < 2; ++k2) {
      int sofs = ((k2 * 4 + quad) ^ lw) * 8;
      half8 af[4], bf[8];
#pragma unroll
      for (int i = 0; i < 4; ++i)
        af[i] = *(const half8*)&As[(wave * 64 + 16 * i + ll) * 64 + sofs];
#pragma unroll
      for (int j = 0; j < 8; ++j)
        bf[j] = *(const half8*)&Bs[(16 * j + ll) * 64 + sofs];
#pragma unroll
      for (int i = 0; i < 4; ++i)
#pragma unroll
        for (int j = 0; j < 8; ++j)
          acc[i][j] = __builtin_amdgcn_mfma_f32_16x16x32_f16(af[i], bf[j], acc[i][j], 0, 0, 0);
    }
  }
#pragma unroll
  for (int j = 0; j < 8; ++j) {
    int n = bn0 + 16 * j + ll;
    float bj = bias[n];
#pragma unroll
    for (int i = 0; i < 4; ++i) {
#pragma unroll
      for (int r = 0; r < 4; ++r) {
        long m = bm0 + wave * 64 + 16 * i + quad * 4 + r;
        float v = acc[i][j][r] + bj;
        if (relu) v = fmaxf(v, 0.f);
        C[m * (long)ldC + n] = (_Float16)v;
      }
    }
  }
}

// ---------------- MFMA fused attention (V prefetched into registers)
__global__ __launch_bounds__(256) void attn_h(
    const _Float16* __restrict__ Qp, int qs,
    const _Float16* __restrict__ Kp, const _Float16* __restrict__ Vp, int ks,
    _Float16* __restrict__ Op, int mode_ca, int l0, int rb0)
{
  __shared__ _Float16 KV[128 * 72];
  __shared__ _Float16 Ps[128 * 136];
  int tid = threadIdx.x;
  int lane = tid & 63, wave = tid >> 6;
  int ll = lane & 15, quad = lane >> 4;
  int idx = blockIdx.x;
  int n = idx & 7;
  int rl = idx >> 3;
  long obase = (long)rl * 128 * 512 + n * 64;
  long qoff, koff;
  if (!mode_ca) {
    qoff = (long)rl * 128 * qs + n * 64;
    koff = (long)rl * 128 * ks + n * 64;
  } else {
    int g = rb0 + rl;
    int a = g >> 5;
    int qblk = l0 ? (g & 31) : rl;
    qoff = (long)qblk * 128 * qs + n * 64;
    koff = (long)a * 128 * ks + n * 64;
  }
  // stage K tile; prefetch Q and V from global before first barrier
#pragma unroll
  for (int it = 0; it < 4; ++it) {
    int e = tid + it * 256;
    int r = e >> 3, c = (e & 7) * 8;
    *(half8*)&KV[r * 72 + c] = *(const half8*)&Kp[koff + (long)r * ks + c];
  }
  half8 aQ[2][2];
#pragma unroll
  for (int i = 0; i < 2; ++i)
#pragma unroll
    for (int k2 = 0; k2 < 2; ++k2)
      aQ[i][k2] = *(const half8*)&Qp[qoff + (long)(wave * 32 + i * 16 + ll) * qs
                                     + quad * 8 + k2 * 32];
  half8 vreg[4];
#pragma unroll
  for (int it = 0; it < 4; ++it) {
    int e = tid + it * 256;
    int vr = e >> 3, c = (e & 7) * 8;
    vreg[it] = *(const half8*)&Vp[koff + (long)vr * ks + c];
  }
  __syncthreads();
  floatx4 accS[2][8];
#pragma unroll
  for (int i = 0; i < 2; ++i)
#pragma unroll
    for (int j = 0; j < 8; ++j) accS[i][j] = (floatx4){0.f, 0.f, 0.f, 0.f};
#pragma unroll
  for (int k2 = 0; k2 < 2; ++k2) {
#pragma unroll
    for (int j = 0; j < 8; ++j) {
      half8 bK = *(const half8*)&KV[(j * 16 + ll) * 72 + quad * 8 + k2 * 32];
      accS[0][j] = __builtin_amdgcn_mfma_f32_16x16x32_f16(aQ[0][k2], bK, accS[0][j], 0, 0, 0);
      accS[1][j] = __builtin_amdgcn_mfma_f32_16x16x32_f16(aQ[1][k2], bK, accS[1][j], 0, 0, 0);
    }
  }
  float rinv[2][4];
#pragma unroll
  for (int i = 0; i < 2; ++i) {
#pragma unroll
    for (int r = 0; r < 4; ++r) {
      float mx = -1e30f;
#pragma unroll
      for (int j = 0; j < 8; ++j) {
        accS[i][j][r] *= 0.125f;
        mx = fmaxf(mx, accS[i][j][r]);
      }
#pragma unroll
      for (int off = 1; off < 16; off <<= 1) mx = fmaxf(mx, __shfl_xor(mx, off));
      float s = 0.f;
#pragma unroll
      for (int j = 0; j < 8; ++j) {
        float e = __expf(accS[i][j][r] - mx);
        accS[i][j][r] = e;
        s += e;
      }
#pragma unroll
      for (int off = 1; off < 16; off <<= 1) s += __shfl_xor(s, off);
      rinv[i][r] = 1.f / s;
      int prow = wave * 32 + i * 16 + quad * 4 + r;
#pragma unroll
      for (int j = 0; j < 8; ++j)
        Ps[prow * 136 + j * 16 + ll] = (_Float16)accS[i][j][r];
    }
  }
  __syncthreads();   // K reads done; Ps visible
  // write prefetched V transposed: Vt[h][seq] at KV[h*132 + seq]
#pragma unroll
  for (int it = 0; it < 4; ++it) {
    int e = tid + it * 256;
    int vr = e >> 3, c = (e & 7) * 8;
#pragma unroll
    for (int j = 0; j < 8; ++j) KV[(c + j) * 132 + vr] = vreg[it][j];
  }
  __syncthreads();
  floatx4 accO[2][4];
#pragma unroll
  for (int i = 0; i < 2; ++i)
#pragma unroll
    for (int j = 0; j < 4; ++j) accO[i][j] = (floatx4){0.f, 0.f, 0.f, 0.f};
#pragma unroll
  for (int k4 = 0; k4 < 4; ++k4) {
    half8 aP[2];
#pragma unroll
    for (int i = 0; i < 2; ++i)
      aP[i] = *(const half8*)&Ps[(wave * 32 + i * 16 + ll) * 136 + quad * 8 + k4 * 32];
#pragma unroll
    for (int jh = 0; jh < 4; ++jh) {
      int vb = (jh * 16 + ll) * 132 + quad * 8 + k4 * 32;
      half4 v0 = *(const half4*)&KV[vb];
      half4 v1 = *(const half4*)&KV[vb + 4];
      half8 bV = __builtin_shufflevector(v0, v1, 0, 1, 2, 3, 4, 5, 6, 7);
      accO[0][jh] = __builtin_amdgcn_mfma_f32_16x16x32_f16(aP[0], bV, accO[0][jh], 0, 0, 0);
      accO[1][jh] = __builtin_amdgcn_mfma_f32_16x16x32_f16(aP[1], bV, accO[1][jh], 0, 0, 0);
    }
  }
#pragma unroll
  for (int i = 0; i < 2; ++i)
#pragma unroll
    for (int jh = 0; jh < 4; ++jh)
#pragma unroll
      for (int r = 0; r < 4; ++r) {
        int m = wave * 32 + i * 16 + quad * 4 + r;
        Op[obase + (long)m * 512 + jh * 16 + ll] = (_Float16)(accO[i][jh][r] * rinv[i][r]);
      }
}

// ---------------- Residual + LayerNorm (rows of 512, fp32 math). One wave per row.
__global__ __launch_bounds__(256) void ln_h(
    const void* __restrict__ xin, int xf32, const _Float16* __restrict__ add,
    _Float16* __restrict__ out, const float* __restrict__ g,
    const float* __restrict__ bt, long row0, int bmask)
{
  int rl = blockIdx.x * 4 + (threadIdx.x >> 6);
  long row = row0 + rl;
  int lane = threadIdx.x & 63;
  long xr = (row & (long)bmask) * 512 + lane * 8;
  float v[8];
  if (xf32) {
    float4 a0 = *(const float4*)((const float*)xin + xr);
    float4 a1 = *(const float4*)((const float*)xin + xr + 4);
    v[0] = a0.x; v[1] = a0.y; v[2] = a0.z; v[3] = a0.w;
    v[4] = a1.x; v[5] = a1.y; v[6] = a1.z; v[7] = a1.w;
  } else {
    half8 h = *(const half8*)((const _Float16*)xin + xr);
#pragma unroll
    for (int i = 0; i < 8; ++i) v[i] = (float)h[i];
  }
  if (add) {
    half8 a = *(const half8*)&add[(long)rl * 512 + lane * 8];
#pragma unroll
    for (int i = 0; i < 8; ++i) v[i] += (float)a[i];
  }
  float s = 0.f, sq = 0.f;
#pragma unroll
  for (int i = 0; i < 8; ++i) { s += v[i]; sq += v[i] * v[i]; }
#pragma unroll
  for (int off = 1; off < 64; off <<= 1) {
    s += __shfl_xor(s, off);
    sq += __shfl_xor(sq, off);
  }
  float mean = s * (1.f / 512.f);
  float var = sq * (1.f / 512.f) - mean * mean;
  float rst = rsqrtf(var + 1e-6f);
  int c = lane * 8;
  float4 g0 = *(const float4*)&g[c], g1 = *(const float4*)&g[c + 4];
  float4 b0 = *(const float4*)&bt[c], b1 = *(const float4*)&bt[c + 4];
  float gg[8] = {g0.x, g0.y, g0.z, g0.w, g1.x, g1.y, g1.z, g1.w};
  float bb[8] = {b0.x, b0.y, b0.z, b0.w, b1.x, b1.y, b1.z, b1.w};
  half8 o;
#pragma unroll
  for (int i = 0; i < 8; ++i) o[i] = (_Float16)((v[i] - mean) * rst * gg[i] + bb[i]);
  *(half8*)&out[row * 512 + c] = o;
}

// ---------------- batched 512x512 transpose-convert (12 weights in one launch)
__global__ __launch_bounds__(256) void tconv512(
    const float* __restrict__ w0, const float* __restrict__ w1,
    const float* __restrict__ w2, const float* __restrict__ w3,
    const float* __restrict__ w4, const float* __restrict__ w5,
    _Float16* __restrict__ Wh)
{
  __shared__ float T[64][65];
  int z = blockIdx.z;
  int t = z >> 1, l = z & 1;
  const float* src;
  long off;
  switch (t) {
    case 0: src = w0; off = 0; break;
    case 1: src = w1; off = 262144; break;
    case 2: src = w2; off = 524288; break;
    case 3: src = w3; off = 1048576; break;
    case 4: src = w4; off = 1310720; break;
    default: src = w5; off = 1572864; break;
  }
  src += (long)l * 262144;
  _Float16* out = Wh + (long)l * 4194304 + off;
  int tx = threadIdx.x & 63, tg = threadIdx.x >> 6;
  int r0 = blockIdx.y * 64, c0 = blockIdx.x * 64;
#pragma unroll
  for (int i = 0; i < 16; ++i)
    T[tg + 4 * i][tx] = src[(long)(r0 + tg + 4 * i) * 512 + c0 + tx];
  __syncthreads();
#pragma unroll
  for (int i = 0; i < 16; ++i)
    out[(long)(c0 + tg + 4 * i) * 512 + r0 + tx] = (_Float16)T[tx][tg + 4 * i];
}

// ---------------- layered transpose-convert for FFN weights
__global__ __launch_bounds__(256) void tconvL(const float* __restrict__ in,
                                              _Float16* __restrict__ out, int Rr, int Cc,
                                              long ils, long ols)
{
  __shared__ float T[64][65];
  in += (long)blockIdx.z * ils;
  out += (long)blockIdx.z * ols;
  int tx = threadIdx.x & 63, tg = threadIdx.x >> 6;
  int r0 = blockIdx.y * 64, c0 = blockIdx.x * 64;
#pragma unroll
  for (int i = 0; i < 16; ++i)
    T[tg + 4 * i][tx] = in[(long)(r0 + tg + 4 * i) * Cc + c0 + tx];
  __syncthreads();
#pragma unroll
  for (int i = 0; i < 16; ++i)
    out[(long)(c0 + tg + 4 * i) * Rr + r0 + tx] = (_Float16)T[tx][tg + 4 * i];
}

// ---------------- batched wo conversion
__global__ void woconvB(const float* __restrict__ sa_wo, const float* __restrict__ ca_wo,
                        _Float16* __restrict__ Wh)
{
  int z = blockIdx.y;
  int s = z >> 1, l = z & 1;
  const float* wo = (s ? ca_wo : sa_wo) + (long)l * 262144;
  _Float16* out = Wh + (long)l * 4194304 + (s ? 1835008 : 786432);
  int o = blockIdx.x * 256 + threadIdx.x;  // 262144
  int d = o >> 9;
  int nh = o & 511;
  int n = nh >> 6, h = nh & 63;
  out[o] = (_Float16)wo[((long)(n << 9) + d) * 64 + h];
}

// ---------------- pack all biases in one launch
__global__ void packbias(const float* __restrict__ sa_bq, const float* __restrict__ sa_bk,
                         const float* __restrict__ sa_bv, const float* __restrict__ ca_bk,
                         const float* __restrict__ ca_bv, float* __restrict__ Bqkv,
                         float* __restrict__ Bkv)
{
  int i = blockIdx.x * 256 + threadIdx.x;
  if (i >= 5120) return;
  int reg = i >> 9, idx = i & 511;
  int l = reg / 5, r = reg % 5;
  int lo = l * 512;
  switch (r) {
    case 0: Bqkv[l * 1536 + idx] = sa_bq[lo + idx]; break;
    case 1: Bqkv[l * 1536 + 512 + idx] = sa_bk[lo + idx]; break;
    case 2: Bqkv[l * 1536 + 1024 + idx] = sa_bv[lo + idx]; break;
    case 3: Bkv[l * 1024 + idx] = ca_bk[lo + idx]; break;
    default: Bkv[l * 1024 + 512 + idx] = ca_bv[lo + idx]; break;
  }
}

// ---------------- fused fp32->fp16 for c and q
__global__ void f2h2(const float* __restrict__ a, _Float16* __restrict__ oa, long na,
                     const float* __restrict__ bsrc, _Float16* __restrict__ ob, long nb)
{
  long i = blockIdx.x * 256L + threadIdx.x;
  if (i < na) oa[i] = (_Float16)a[i];
  else if (i < na + nb) ob[i - na] = (_Float16)bsrc[i - na];
}

// ---------------- fused pool(q fp32) + feature + normalize -> QN (8 x 256)
__global__ void featq_pool(const float* __restrict__ q, const float* __restrict__ W,
                           const float* __restrict__ bias, float* __restrict__ QN)
{
  __shared__ float sh[512];
  __shared__ float red[256];
  int a = blockIdx.x;
  int f = threadIdx.x;
  for (int dd = f; dd < 512; dd += 256) {
    const float* base = q + (long)a * 65536 + dd;
    float s = 0.f;
    for (int t = 1; t < 128; ++t) s += base[t * 512];
    sh[dd] = s * (1.f / 127.f);
  }
  __syncthreads();
  float acc = bias[f];
  for (int d = 0; d < 512; ++d) acc += sh[d] * W[d * 256 + f];
  red[f] = acc * acc;
  __syncthreads();
  for (int s = 128; s > 0; s >>= 1) {
    if (f < s) red[f] += red[f + s];
    __syncthreads();
  }
  float rn = rsqrtf(fmaxf(red[0], 1e-12f));
  QN[a * 256 + f] = acc * rn;
}

// ---------------- fused pool(X fp16) + feature + normalize + dot(QN) -> out (256)
__global__ void featc_pool(const _Float16* __restrict__ X, const float* __restrict__ W,
                           const float* __restrict__ bias, const float* __restrict__ QN,
                           float* __restrict__ out)
{
  __shared__ float sh[512];
  __shared__ float red[256];
  int ab = blockIdx.x;
  int f = threadIdx.x;
  for (int dd = f; dd < 512; dd += 256) {
    const _Float16* base = X + (long)ab * 65536 + dd;
    float s = 0.f;
    for (int t = 1; t < 128; ++t) s += (float)base[t * 512];
    sh[dd] = s * (1.f / 127.f);
  }
  __syncthreads();
  float acc = bias[f];
  for (int d = 0; d < 512; ++d) acc += sh[d] * W[d * 256 + f];
  red[f] = acc * acc;
  __syncthreads();
  for (int s = 128; s > 0; s >>= 1) {
    if (f < s) red[f] += red[f + s];
    __syncthreads();
  }
  float rn = rsqrtf(fmaxf(red[0], 1e-12f));
  float v = acc * rn * QN[(ab >> 5) * 256 + f];
  __syncthreads();
  red[f] = v;
  __syncthreads();
  for (int s = 128; s > 0; s >>= 1) {
    if (f < s) red[f] += red[f + s];
    __syncthreads();
  }
  if (f == 0) out[ab] = red[0];
}

extern "C" void kernel_launch(void* const* d_in, const int* in_sizes, int n_in,
                              void* d_out, int out_size, void* d_ws, size_t ws_size,
                              hipStream_t stream)
{
  (void)in_sizes; (void)n_in; (void)out_size;
  const float* c_in  = (const float*)d_in[0];
  const float* q_in  = (const float*)d_in[1];
  const float* sa_wq = (const float*)d_in[2];
  const float* sa_bq = (const float*)d_in[3];
  const float* sa_wk = (const float*)d_in[4];
  const float* sa_bk = (const float*)d_in[5];
  const float* sa_wv = (const float*)d_in[6];
  const float* sa_bv = (const float*)d_in[7];
  const float* sa_wo = (const float*)d_in[8];
  const float* sa_bo = (const float*)d_in[9];
  const float* ca_wq = (const float*)d_in[10];
  const float* ca_bq = (const float*)d_in[11];
  const float* ca_wk = (const float*)d_in[12];
  const float* ca_bk = (const float*)d_in[13];
  const float* ca_wv = (const float*)d_in[14];
  const float* ca_bv = (const float*)d_in[15];
  const float* ca_wo = (const float*)d_in[16];
  const float* ca_bo = (const float*)d_in[17];
  const float* ln1_g = (const float*)d_in[18];
  const float* ln1_b = (const float*)d_in[19];
  const float* ln2_g = (const float*)d_in[20];
  const float* ln2_b = (const float*)d_in[21];
  const float* ln3_g = (const float*)d_in[22];
  const float* ln3_b = (const float*)d_in[23];
  const float* ffn_w1 = (const float*)d_in[24];
  const float* ffn_b1 = (const float*)d_in[25];
  const float* ffn_w2 = (const float*)d_in[26];
  const float* ffn_b2 = (const float*)d_in[27];
  const float* lnf_g  = (const float*)d_in[28];
  const float* lnf_b  = (const float*)d_in[29];
  const float* feat_wq = (const float*)d_in[30];
  const float* feat_bq = (const float*)d_in[31];
  const float* feat_wc = (const float*)d_in[32];
  const float* feat_bc = (const float*)d_in[33];

  // ---- workspace layout
  char* p = (char*)d_ws;
  _Float16* Xh  = (_Float16*)p;  p += 33554432;  // 32768 x 512 fp16 residual stream
  _Float16* Xsh = (_Float16*)p;  p += 4194304;   //  4096 x 512 fp16 (layer-0 x)
  _Float16* Wh  = (_Float16*)p;  p += 16777216;  // fp16 weight arena (2 layers)
  _Float16* qh  = (_Float16*)p;  p += 1048576;   //  1024 x 512 fp16
  _Float16* KV0 = (_Float16*)p;  p += 2097152;   //  1024 x 1024 fp16 (K|V)
  float*    Bqkv = (float*)p;    p += 12288;
  float*    Bkv  = (float*)p;    p += 8192;
  float*    QN  = (float*)p;     p += 8192;
  const size_t fixed_b = (size_t)(p - (char*)d_ws);
  long R = 4096;
  if (ws_size >= fixed_b + 5120UL * 32768) R = 32768;
  else if (ws_size >= fixed_b + 5120UL * 16384) R = 16384;
  else if (ws_size >= fixed_b + 5120UL * 8192) R = 8192;
  _Float16* QKVc = (_Float16*)p; p += R * 3072;  // [R][1536]
  _Float16* Oc   = (_Float16*)p; p += R * 1024;  // [R][512]
  _Float16* Ac   = (_Float16*)p;                 // [R][512]
  _Float16* Hb = QKVc;            // FFN hidden [R][2048] spans QKVc+Oc (contiguous)
  const int MTR = (int)(R / 256);

  // ---- prep (6 launches)
  f2h2<<<10240, 256, 0, stream>>>(c_in, Xsh, 2097152, q_in, qh, 524288);
  tconv512<<<dim3(8, 8, 12), 256, 0, stream>>>(sa_wq, sa_wk, sa_wv, ca_wq, ca_wk, ca_wv, Wh);
  woconvB<<<dim3(1024, 4), 256, 0, stream>>>(sa_wo, ca_wo, Wh);
  tconvL<<<dim3(32, 8, 2), 256, 0, stream>>>(ffn_w1, Wh + 2097152, 512, 2048, 1048576, 4194304);
  tconvL<<<dim3(8, 32, 2), 256, 0, stream>>>(ffn_w2, Wh + 3145728, 2048, 512, 1048576, 4194304);
  packbias<<<20, 256, 0, stream>>>(sa_bq, sa_bk, sa_bv, ca_bk, ca_bv, Bqkv, Bkv);

  // =================== layer 0 (x rows = 4096) ===================
  {
    _Float16* Wl = Wh;
    gemm_h<<<dim3(12, 32), 256, 0, stream>>>(Xsh, Wl + 0, Bqkv, QKVc, 4096, 1536, 512, 1536, 0);
    attn_h<<<256, 256, 0, stream>>>(QKVc, 1536, QKVc + 512, QKVc + 1024, 1536, Oc, 0, 0, 0);
    gemm_h<<<dim3(4, 32), 256, 0, stream>>>(Oc, Wl + 786432, sa_bo, Ac, 4096, 512, 512, 512, 0);
    ln_h<<<1024, 256, 0, stream>>>(c_in, 1, Ac, Xsh, ln1_g, ln1_b, 0, 0x7FFFFFFF);
    gemm_h<<<dim3(4, 32), 256, 0, stream>>>(Xsh, Wl + 1048576, ca_bq, QKVc, 4096, 512, 512, 1536, 0);
    gemm_h<<<dim3(8, 8), 256, 0, stream>>>(qh, Wl + 1310720, Bkv, KV0, 1024, 1024, 512, 1024, 0);
    for (long c = 0; c < 32768; c += R) {
      attn_h<<<(R / 128) * 8, 256, 0, stream>>>(QKVc, 1536, KV0, KV0 + 512, 1024, Oc,
                                                1, 1, (int)(c / 128));
      gemm_2<<<MTR * 4, 256, 0, stream>>>(Oc, Wl + 1835008, ca_bo, Ac, MTR, 4, 512, 512, 0);
      ln_h<<<R / 4, 256, 0, stream>>>(Xsh, 0, Ac, Xh, ln2_g, ln2_b, c, 4095);
      gemm_2<<<MTR * 16, 256, 0, stream>>>(Xh + c * 512, Wl + 2097152,
                                           ffn_b1, Hb, MTR, 16, 512, 2048, 1);
      gemm_2<<<MTR * 4, 256, 0, stream>>>(Hb, Wl + 3145728, ffn_b2, Ac, MTR, 4, 2048, 512, 0);
      ln_h<<<R / 4, 256, 0, stream>>>(Xh, 0, Ac, Xh, ln3_g, ln3_b, c, 0x7FFFFFFF);
    }
  }
  // =================== layer 1 (x rows = 32768) ===================
  {
    _Float16* Wl = Wh + 4194304;
    gemm_h<<<dim3(8, 8), 256, 0, stream>>>(qh, Wl + 1310720, Bkv + 1024, KV0, 1024, 1024, 512, 1024, 0);
    for (long c = 0; c < 32768; c += R) {
      _Float16* Xhc = Xh + c * 512;
      gemm_2<<<MTR * 12, 256, 0, stream>>>(Xhc, Wl + 0, Bqkv + 1536, QKVc, MTR, 12, 512, 1536, 0);
      attn_h<<<(R / 128) * 8, 256, 0, stream>>>(QKVc, 1536, QKVc + 512, QKVc + 1024, 1536,
                                                Oc, 0, 0, 0);
      gemm_2<<<MTR * 4, 256, 0, stream>>>(Oc, Wl + 786432, sa_bo + 512, Ac, MTR, 4, 512, 512, 0);
      ln_h<<<R / 4, 256, 0, stream>>>(Xh, 0, Ac, Xh, ln1_g + 512, ln1_b + 512, c, 0x7FFFFFFF);
      gemm_2<<<MTR * 4, 256, 0, stream>>>(Xhc, Wl + 1048576, ca_bq + 512, QKVc, MTR, 4, 512, 1536, 0);
      attn_h<<<(R / 128) * 8, 256, 0, stream>>>(QKVc, 1536, KV0, KV0 + 512, 1024, Oc,
                                                1, 0, (int)(c / 128));
      gemm_2<<<MTR * 4, 256, 0, stream>>>(Oc, Wl + 1835008, ca_bo + 512, Ac, MTR, 4, 512, 512, 0);
      ln_h<<<R / 4, 256, 0, stream>>>(Xh, 0, Ac, Xh, ln2_g + 512, ln2_b + 512, c, 0x7FFFFFFF);
      gemm_2<<<MTR * 16, 256, 0, stream>>>(Xh + c * 512, Wl + 2097152,
                                           ffn_b1 + 2048, Hb, MTR, 16, 512, 2048, 1);
      gemm_2<<<MTR * 4, 256, 0, stream>>>(Hb, Wl + 3145728, ffn_b2 + 512, Ac, MTR, 4, 2048, 512, 0);
      ln_h<<<R / 4, 256, 0, stream>>>(Xh, 0, Ac, Xh, ln3_g + 512, ln3_b + 512, c, 0x7FFFFFFF);
    }
  }
  // =================== final LN + fused pool/features/cosine ===================
  ln_h<<<8192, 256, 0, stream>>>(Xh, 0, nullptr, Xh, lnf_g, lnf_b, 0, 0x7FFFFFFF);
  featq_pool<<<8, 256, 0, stream>>>(q_in, feat_wq, feat_bq, QN);
  featc_pool<<<256, 256, 0, stream>>>(Xh, feat_wc, feat_bc, QN, (float*)d_out);
}